// Round 11
// baseline (141.917 us; speedup 1.0000x reference)
//
#include <hip/hip_runtime.h>
#include <math.h>

typedef _Float16 half8 __attribute__((ext_vector_type(8)));
typedef float f32x4 __attribute__((ext_vector_type(4)));

#define MFMA_F16 __builtin_amdgcn_mfma_f32_16x16x32_f16

constexpr int WS = 7, HH = 56, HW = 3136;

// d_ws layout: fp16 tiles then f32 folded biases
constexpr int QKVP_OFF  = 0;       // 27648 fp16
constexpr int PROJP_OFF = 27648;   // 9216
constexpr int W1P_OFF   = 36864;   // 9216
constexpr int W2P_OFF   = 46080;   // 9216 -> 55296 fp16 = 110592 B
constexpr int BIASF_BYTE = 110592; // f32 [288 qkv' | 96 mlp1'] = 1536 B

__device__ __forceinline__ int lab8(int v) { return v < 49 ? 0 : (v < 53 ? 1 : 2); }
__device__ __forceinline__ int div7h(int v) { return (v * 9363) >> 16; }  // valid 0..63

// ---------------------------------------------------------------------------
// Weight pre-pack with LN-affine folding:
//   qkv tiles row-scaled by ln1_g; w1 tiles row-scaled by ln2_g.
//   bias_out[0..288) = qkv_b + ln1_b^T @ qkv_w ; [288..384) = mlp_b1 + ln2_b^T @ w1
// ---------------------------------------------------------------------------
__global__ __launch_bounds__(256) void pack_w8(
    const float* __restrict__ qkv_w, const float* __restrict__ proj_w,
    const float* __restrict__ w1, const float* __restrict__ w2,
    const float* __restrict__ ln1_g, const float* __restrict__ ln1_b,
    const float* __restrict__ ln2_g, const float* __restrict__ ln2_b,
    const float* __restrict__ qkv_b, const float* __restrict__ mlp_b1,
    _Float16* __restrict__ ws, float* __restrict__ bias_out)
{
    int blk = blockIdx.x;
    if (blk < 216) {
        int i = blk * 256 + threadIdx.x;
        const float* src; int ncol, local; const float* gv = nullptr;
        if (i < 27648)      { src = qkv_w;  ncol = 288; local = i; gv = ln1_g; }
        else if (i < 36864) { src = proj_w; ncol = 96;  local = i - 27648; }
        else if (i < 46080) { src = w1;     ncol = 96;  local = i - 36864; gv = ln2_g; }
        else                { src = w2;     ncol = 96;  local = i - 46080; }
        int j = local & 7, col = (local >> 3) & 15, ksub = (local >> 7) & 3;
        int rest = local >> 9;
        int kb = rest % 3, nt = rest / 3;
        int k = kb * 32 + ksub * 8 + j, n = nt * 16 + col;
        float v = src[k * ncol + n];
        if (gv) v *= gv[k];
        ws[i] = (_Float16)v;
    } else if (blk == 216) {
        int n = threadIdx.x;                   // qkv bias cols 0..255
        float s = qkv_b[n];
        for (int k = 0; k < 96; ++k) s += ln1_b[k] * qkv_w[k * 288 + n];
        bias_out[n] = s;
    } else {
        int t = threadIdx.x;
        if (t < 32) {                          // qkv bias cols 256..287
            int n = 256 + t;
            float s = qkv_b[n];
            for (int k = 0; k < 96; ++k) s += ln1_b[k] * qkv_w[k * 288 + n];
            bias_out[n] = s;
        } else if (t < 128) {                  // mlp bias1 cols
            int n = t - 32;
            float s = mlp_b1[n];
            for (int k = 0; k < 96; ++k) s += ln2_b[k] * w1[k * 96 + n];
            bias_out[288 + n] = s;
        }
    }
}

// ---------------------------------------------------------------------------
// Fully fused Swin block. One block per (batch,window); TWO barriers;
// 36.9 KB LDS -> 4 blocks/CU. LDS planes aliased over time:
//   region A [0,12288):      XLN -> Qu -> Pu(lo) -> Ou -> XT
//   region B [12288,24576):  Ku -> Pu(hi) -> YT
//   region V [24576,36864):  Vu (pad planes zeroed by wave 3 at entry)
// All no-barrier aliases touch only own-wave own-stripe rows (in-order DS).
// ---------------------------------------------------------------------------
__global__ __launch_bounds__(256, 4) void attn_k8(
    const float* __restrict__ x,
    const float* __restrict__ attn_bias,
    const float* __restrict__ proj_b,
    const float* __restrict__ mlp_b2,
    const _Float16* __restrict__ wpack,
    const float* __restrict__ biasf,   // [0,288) qkv folded, [288,384) mlp1 folded
    float* __restrict__ out)
{
    __shared__ __align__(16) char smem[36864];

    _Float16*  XLN = (_Float16*)smem;
    _Float16*  Qu  = (_Float16*)smem;
    _Float16*  Ku  = (_Float16*)(smem + 12288);
    _Float16*  Vu  = (_Float16*)(smem + 24576);
    _Float16*  Pu  = (_Float16*)smem;            // 24 planes spanning A+B
    _Float16*  Ou  = (_Float16*)smem;            // planes 0..11, own rows
    _Float16*  XT  = (_Float16*)smem;
    _Float16*  YT  = (_Float16*)(smem + 12288);

    const _Float16* qkvp  = wpack + QKVP_OFF;
    const _Float16* projp = wpack + PROJP_OFF;
    const _Float16* w1p   = wpack + W1P_OFF;
    const _Float16* w2p   = wpack + W2P_OFF;

    const int blk = blockIdx.x;
    const int b   = blk >> 6;
    const int w   = blk & 63;
    const int wh  = w >> 3, ww = w & 7;
    const int tid = threadIdx.x;
    const int wv  = tid >> 6, lane = tid & 63;
    const int l15 = lane & 15, l4 = lane >> 4;

    // ---- wave 3 zeroes V pad planes (token groups 6,7 per head) ----------
    // Only wave 3 writes V rows >=48, so in-wave DS order makes this safe
    // without a barrier; all other waves' V data lands in groups 0..5.
    if (wv == 3) {
        uint4* v4 = (uint4*)Vu;
        #pragma unroll
        for (int c = 0; c < 3; ++c)
            v4[(c * 8 + 6) * 32 + lane] = make_uint4(0, 0, 0, 0);
    }

    // ---- gather window (rolled) into registers: 4 threads/token ----------
    const int t_own = tid >> 2, part = tid & 3;
    const bool active = (tid < 196);
    float4 xq[6];
    float m = 0.f, rinv = 0.f;
    if (active) {
        int i = div7h(t_own), j = t_own - i * 7;
        int row = wh * WS + i + 3; if (row >= HH) row -= HH;
        int col = ww * WS + j + 3; if (col >= HH) col -= HH;
        const float* xp = &x[(((size_t)b * HW + row * HH + col) * 96) + part * 24];
        #pragma unroll
        for (int q = 0; q < 6; ++q) xq[q] = *(const float4*)&xp[q * 4];
        float sum = 0.f, sq = 0.f;
        #pragma unroll
        for (int q = 0; q < 6; ++q) {
            sum += xq[q].x + xq[q].y + xq[q].z + xq[q].w;
            sq  += xq[q].x * xq[q].x + xq[q].y * xq[q].y
                 + xq[q].z * xq[q].z + xq[q].w * xq[q].w;
        }
        sum += __shfl_xor(sum, 1); sq += __shfl_xor(sq, 1);
        sum += __shfl_xor(sum, 2); sq += __shfl_xor(sq, 2);
        m = sum * (1.0f / 96.0f);
        rinv = rsqrtf(sq * (1.0f / 96.0f) - m * m + 1e-5f);
    }

    // ---- normalize (gamma/beta folded into weights) -> XLN A-tiles -------
    // Row t is written by threads 4t..4t+3 which live in wave t>>4, so the
    // QKV A-fragment reads below (own stripe) need no barrier.
    if (active) {
        #pragma unroll
        for (int cc = 0; cc < 3; ++cc) {
            half8 pk;
            #pragma unroll
            for (int j = 0; j < 8; ++j) {
                float v; int qi = cc * 2 + (j >> 2);
                if ((j & 3) == 0) v = xq[qi].x;
                else if ((j & 3) == 1) v = xq[qi].y;
                else if ((j & 3) == 2) v = xq[qi].z;
                else v = xq[qi].w;
                pk[j] = (_Float16)((v - m) * rinv);
            }
            *(half8*)&XLN[(part * 3 + cc) * 512 + t_own * 8] = pk;
        }
    }

    // ---- QKV GEMM: wave wv owns token tile mt=wv --------------------------
    {
        half8 a[3];
        #pragma unroll
        for (int kb = 0; kb < 3; ++kb)
            a[kb] = *(half8*)&XLN[(kb * 4 + l4) * 512 + (wv * 16 + l15) * 8];
        const int tok0 = wv * 16 + l4 * 4;

        // Q: nt 0..5 (unguarded: garbage rows replaced in softmax)
        #pragma unroll
        for (int nt = 0; nt < 6; ++nt) {
            f32x4 acc = {0.f, 0.f, 0.f, 0.f};
            #pragma unroll
            for (int kb = 0; kb < 3; ++kb) {
                half8 bw = *(const half8*)&qkvp[((nt * 3 + kb) * 4 + l4) * 128 + l15 * 8];
                acc = MFMA_F16(a[kb], bw, acc, 0, 0, 0);
            }
            int n = nt * 16 + l15;
            float bias = biasf[n];
            int h = n >> 5, d = n & 31;
            _Float16* qp = &Qu[(h * 4 + (d >> 3)) * 512 + tok0 * 8 + (d & 7)];
            #pragma unroll
            for (int r = 0; r < 4; ++r)
                qp[r * 8] = (_Float16)(acc[r] + bias);
        }
        // K: nt 6..11 (unguarded)
        #pragma unroll
        for (int nt = 6; nt < 12; ++nt) {
            f32x4 acc = {0.f, 0.f, 0.f, 0.f};
            #pragma unroll
            for (int kb = 0; kb < 3; ++kb) {
                half8 bw = *(const half8*)&qkvp[((nt * 3 + kb) * 4 + l4) * 128 + l15 * 8];
                acc = MFMA_F16(a[kb], bw, acc, 0, 0, 0);
            }
            int n = nt * 16 + l15;
            float bias = biasf[n];
            int n2 = n - 96, h = n2 >> 5, d = n2 & 31;
            _Float16* kp = &Ku[(h * 4 + (d >> 3)) * 512 + tok0 * 8 + (d & 7)];
            #pragma unroll
            for (int r = 0; r < 4; ++r)
                kp[r * 8] = (_Float16)(acc[r] + bias);
        }
        // V: nt 12..17 (guarded: pad rows must stay zero)
        #pragma unroll
        for (int nt = 12; nt < 18; ++nt) {
            f32x4 acc = {0.f, 0.f, 0.f, 0.f};
            #pragma unroll
            for (int kb = 0; kb < 3; ++kb) {
                half8 bw = *(const half8*)&qkvp[((nt * 3 + kb) * 4 + l4) * 128 + l15 * 8];
                acc = MFMA_F16(a[kb], bw, acc, 0, 0, 0);
            }
            int n = nt * 16 + l15;
            float bias = biasf[n];
            int n2 = n - 192, h = n2 >> 5, d = n2 & 31;
            #pragma unroll
            for (int r = 0; r < 4; ++r) {
                int tok = tok0 + r;
                if (tok < 49)
                    Vu[(h * 8 + (tok >> 3)) * 256 + d * 8 + (tok & 7)] = (_Float16)(acc[r] + bias);
            }
        }
    }
    __syncthreads();   // B2: K/V published for cross-wave reads

    // ---- scores: wave wv owns q-tile; all heads, K=32 single MFMA ---------
    f32x4 s[3][4];
    #pragma unroll
    for (int h = 0; h < 3; ++h) {
        half8 qf = *(half8*)&Qu[(h * 4 + l4) * 512 + (wv * 16 + l15) * 8];
        #pragma unroll
        for (int nt = 0; nt < 4; ++nt) {
            half8 kf = *(half8*)&Ku[(h * 4 + l4) * 512 + (nt * 16 + l15) * 8];
            f32x4 z = {0.f, 0.f, 0.f, 0.f};
            s[h][nt] = MFMA_F16(qf, kf, z, 0, 0, 0);
        }
    }

    // ---- prefetch residual x for this wave's tokens (hidden under softmax)
    size_t tbase[4]; bool tvalid[4];
    #pragma unroll
    for (int r = 0; r < 4; ++r) {
        int tok = wv * 16 + l4 * 4 + r;
        tvalid[r] = (tok < 49);
        int i = div7h(tok & 63), j = (tok & 63) - i * 7;
        int row = wh * WS + i + 3; if (row >= HH) row -= HH;
        int col = ww * WS + j + 3; if (col >= HH) col -= HH;
        tbase[r] = ((size_t)b * HW + row * HH + col) * 96;
    }
    float xr[6][4];
    #pragma unroll
    for (int nt = 0; nt < 6; ++nt) {
        int n = nt * 16 + l15;
        #pragma unroll
        for (int r = 0; r < 4; ++r)
            xr[nt][r] = tvalid[r] ? x[tbase[r] + n] : 0.f;
    }
    __syncthreads();   // B3: Q,K dead for ALL waves -> P may overwrite A+B

    // ---- softmax (no max-subtraction; scores bounded) -> P tiles ----------
    {
        const float scale = 0.17677669529663687f;
        int qq[4]; bool qo[4]; int kc[4];
        bool keep[4][4];
        #pragma unroll
        for (int nt = 0; nt < 4; ++nt) {
            int k = nt * 16 + l15;
            kc[nt] = k < 49 ? k : 48;
        }
        #pragma unroll
        for (int r = 0; r < 4; ++r) {
            qq[r] = wv * 16 + l4 * 4 + r;
            qo[r] = qq[r] < 49;
            int qcl = qo[r] ? qq[r] : 48;
            int qi = div7h(qcl), qj = qcl - qi * 7;
            int lqr = lab8(wh * WS + qi), lqc = lab8(ww * WS + qj);
            #pragma unroll
            for (int nt = 0; nt < 4; ++nt) {
                int k = nt * 16 + l15;
                int ki = div7h(kc[nt]), kj = kc[nt] - ki * 7;
                keep[r][nt] = qo[r] && (k < 49) &&
                              (lqr == lab8(wh * WS + ki)) &&
                              (lqc == lab8(ww * WS + kj));
            }
        }
        #pragma unroll
        for (int h = 0; h < 3; ++h) {
            #pragma unroll
            for (int r = 0; r < 4; ++r) {
                int qcl = qo[r] ? qq[r] : 48;
                const float* bp = attn_bias + (h * 49 + qcl) * 49;
                float e[4], sum = 0.f;
                #pragma unroll
                for (int nt = 0; nt < 4; ++nt) {
                    float v = fmaf(s[h][nt][r], scale, bp[kc[nt]]);
                    e[nt] = keep[r][nt] ? __expf(v) : 0.f;
                    sum += e[nt];
                }
                sum += __shfl_xor(sum, 1);
                sum += __shfl_xor(sum, 2);
                sum += __shfl_xor(sum, 4);
                sum += __shfl_xor(sum, 8);
                float inv = qo[r] ? __builtin_amdgcn_rcpf(sum) : 0.f;
                #pragma unroll
                for (int nt = 0; nt < 4; ++nt) {
                    int k = nt * 16 + l15;
                    Pu[(h * 8 + (k >> 3)) * 512 + qq[r] * 8 + (k & 7)] =
                        (_Float16)(e[nt] * inv);
                }
            }
        }
    }
    // Everything below: wave-private own-stripe rows or read-only V.

    // ---- PV: O = P @ V (own q-stripe); O over own P rows ------------------
    #pragma unroll
    for (int h = 0; h < 3; ++h) {
        half8 pa0 = *(half8*)&Pu[(h * 8 + 0 + l4) * 512 + (wv * 16 + l15) * 8];
        half8 pa1 = *(half8*)&Pu[(h * 8 + 4 + l4) * 512 + (wv * 16 + l15) * 8];
        #pragma unroll
        for (int ntd = 0; ntd < 2; ++ntd) {
            f32x4 acc = {0.f, 0.f, 0.f, 0.f};
            half8 vb0 = *(half8*)&Vu[(h * 8 + 0 + l4) * 256 + (ntd * 16 + l15) * 8];
            acc = MFMA_F16(pa0, vb0, acc, 0, 0, 0);
            half8 vb1 = *(half8*)&Vu[(h * 8 + 4 + l4) * 256 + (ntd * 16 + l15) * 8];
            acc = MFMA_F16(pa1, vb1, acc, 0, 0, 0);
            int c = h * 32 + ntd * 16 + l15;
            #pragma unroll
            for (int r = 0; r < 4; ++r) {
                int tok = wv * 16 + l4 * 4 + r;
                Ou[(c >> 3) * 512 + tok * 8 + (c & 7)] = (_Float16)acc[r];
            }
        }
    }

    // ---- proj + residual into registers (x2 = x + attn_out) --------------
    float x2v[6][4];
    {
        half8 oa[3];
        #pragma unroll
        for (int kb = 0; kb < 3; ++kb)
            oa[kb] = *(half8*)&Ou[(kb * 4 + l4) * 512 + (wv * 16 + l15) * 8];
        for (int nt = 0; nt < 6; ++nt) {
            f32x4 acc = {0.f, 0.f, 0.f, 0.f};
            #pragma unroll
            for (int kb = 0; kb < 3; ++kb) {
                half8 bw = *(const half8*)&projp[((nt * 3 + kb) * 4 + l4) * 128 + l15 * 8];
                acc = MFMA_F16(oa[kb], bw, acc, 0, 0, 0);
            }
            int n = nt * 16 + l15;
            float pb = proj_b[n];
            #pragma unroll
            for (int r = 0; r < 4; ++r)
                x2v[nt][r] = tvalid[r] ? (xr[nt][r] + acc[r] + pb) : 0.f;
        }
    }

    // ---- LN2 in-register (gamma/beta folded into w1/bias1) ----------------
    float mu2[4], rs2[4];
    #pragma unroll
    for (int r = 0; r < 4; ++r) {
        float sum = 0.f, sq = 0.f;
        #pragma unroll
        for (int nt = 0; nt < 6; ++nt) { float v = x2v[nt][r]; sum += v; sq += v * v; }
        sum += __shfl_xor(sum, 1); sq += __shfl_xor(sq, 1);
        sum += __shfl_xor(sum, 2); sq += __shfl_xor(sq, 2);
        sum += __shfl_xor(sum, 4); sq += __shfl_xor(sq, 4);
        sum += __shfl_xor(sum, 8); sq += __shfl_xor(sq, 8);
        float mm = sum * (1.0f / 96.0f);
        mu2[r] = mm;
        rs2[r] = rsqrtf(sq * (1.0f / 96.0f) - mm * mm + 1e-5f);
    }

    // ---- x^ -> XT A-tiles (own rows; overwrites Ou after oa read) ---------
    #pragma unroll
    for (int nt = 0; nt < 6; ++nt) {
        int n = nt * 16 + l15;
        #pragma unroll
        for (int r = 0; r < 4; ++r) {
            int tok = wv * 16 + l4 * 4 + r;
            XT[(n >> 3) * 512 + tok * 8 + (n & 7)] =
                (_Float16)((x2v[nt][r] - mu2[r]) * rs2[r]);
        }
    }

    // ---- MLP GEMM1 + GELU -> YT tiles (own rows, over P-hi) ---------------
    {
        half8 a[3];
        #pragma unroll
        for (int kb = 0; kb < 3; ++kb)
            a[kb] = *(half8*)&XT[(kb * 4 + l4) * 512 + (wv * 16 + l15) * 8];
        for (int nt = 0; nt < 6; ++nt) {
            f32x4 acc = {0.f, 0.f, 0.f, 0.f};
            #pragma unroll
            for (int kb = 0; kb < 3; ++kb) {
                half8 bw = *(const half8*)&w1p[((nt * 3 + kb) * 4 + l4) * 128 + l15 * 8];
                acc = MFMA_F16(a[kb], bw, acc, 0, 0, 0);
            }
            int n = nt * 16 + l15;
            float bias = biasf[288 + n];
            #pragma unroll
            for (int r = 0; r < 4; ++r) {
                int tok = wv * 16 + l4 * 4 + r;
                float v = acc[r] + bias;
                // gelu(v) ~= v * sigmoid(v*(1.5957691 + 0.0713548*v^2))
                float v2 = v * v;
                float c2 = fmaf(v2, 0.0713548163f, 1.5957691216f);
                float z  = v * c2;
                float ex = __expf(-z);
                float y  = v * __builtin_amdgcn_rcpf(1.0f + ex);
                YT[(n >> 3) * 512 + tok * 8 + (n & 7)] = (_Float16)y;
            }
        }
    }

    // ---- MLP GEMM2 + final residual -> out --------------------------------
    {
        half8 a[3];
        #pragma unroll
        for (int kb = 0; kb < 3; ++kb)
            a[kb] = *(half8*)&YT[(kb * 4 + l4) * 512 + (wv * 16 + l15) * 8];
        for (int nt = 0; nt < 6; ++nt) {
            f32x4 acc = {0.f, 0.f, 0.f, 0.f};
            #pragma unroll
            for (int kb = 0; kb < 3; ++kb) {
                half8 bw = *(const half8*)&w2p[((nt * 3 + kb) * 4 + l4) * 128 + l15 * 8];
                acc = MFMA_F16(a[kb], bw, acc, 0, 0, 0);
            }
            int n = nt * 16 + l15;
            float bias = mlp_b2[n];
            #pragma unroll
            for (int r = 0; r < 4; ++r) {
                if (tvalid[r])
                    out[tbase[r] + n] = x2v[nt][r] + acc[r] + bias;
            }
        }
    }
}

extern "C" void kernel_launch(void* const* d_in, const int* in_sizes, int n_in,
                              void* d_out, int out_size, void* d_ws, size_t ws_size,
                              hipStream_t stream) {
    (void)in_sizes; (void)n_in; (void)ws_size; (void)out_size;
    const float* x         = (const float*)d_in[0];
    const float* qkv_w     = (const float*)d_in[1];
    const float* qkv_b     = (const float*)d_in[2];
    const float* attn_bias = (const float*)d_in[3];
    const float* proj_w    = (const float*)d_in[4];
    const float* proj_b    = (const float*)d_in[5];
    const float* ln1_g     = (const float*)d_in[6];
    const float* ln1_b     = (const float*)d_in[7];
    const float* ln2_g     = (const float*)d_in[8];
    const float* ln2_b     = (const float*)d_in[9];
    const float* mlp_w1    = (const float*)d_in[10];
    const float* mlp_b1    = (const float*)d_in[11];
    const float* mlp_w2    = (const float*)d_in[12];
    const float* mlp_b2    = (const float*)d_in[13];
    float* out = (float*)d_out;
    _Float16* wpack = (_Float16*)d_ws;
    float* biasf = (float*)((char*)d_ws + BIASF_BYTE);

    pack_w8<<<218, 256, 0, stream>>>(qkv_w, proj_w, mlp_w1, mlp_w2,
                                     ln1_g, ln1_b, ln2_g, ln2_b,
                                     qkv_b, mlp_b1, wpack, biasf);
    attn_k8<<<64 * 64, 256, 0, stream>>>(x, attn_bias, proj_b, mlp_b2,
                                         wpack, biasf, out);
}

// Round 12
// 140.711 us; speedup vs baseline: 1.0086x; 1.0086x over previous
//
#include <hip/hip_runtime.h>
#include <math.h>

typedef _Float16 half8 __attribute__((ext_vector_type(8)));
typedef float f32x4 __attribute__((ext_vector_type(4)));

#define MFMA_F16 __builtin_amdgcn_mfma_f32_16x16x32_f16

constexpr int WS = 7, HH = 56, HW = 3136;

// d_ws layout: fp16 tiles then f32 folded biases
constexpr int QKVP_OFF  = 0;       // 27648 fp16
constexpr int PROJP_OFF = 27648;   // 9216
constexpr int W1P_OFF   = 36864;   // 9216
constexpr int W2P_OFF   = 46080;   // 9216 -> 55296 fp16 = 110592 B
constexpr int BIASF_BYTE = 110592; // f32 [288 qkv' | 96 mlp1'] = 1536 B

__device__ __forceinline__ int lab9(int v) { return v < 49 ? 0 : (v < 53 ? 1 : 2); }
__device__ __forceinline__ int div7i(int v) { return (v * 9363) >> 16; }  // valid 0..63

// ---------------------------------------------------------------------------
// Weight pre-pack with LN-affine folding (identical to R10's pack_w8).
// ---------------------------------------------------------------------------
__global__ __launch_bounds__(256) void pack_w9(
    const float* __restrict__ qkv_w, const float* __restrict__ proj_w,
    const float* __restrict__ w1, const float* __restrict__ w2,
    const float* __restrict__ ln1_g, const float* __restrict__ ln1_b,
    const float* __restrict__ ln2_g, const float* __restrict__ ln2_b,
    const float* __restrict__ qkv_b, const float* __restrict__ mlp_b1,
    _Float16* __restrict__ ws, float* __restrict__ bias_out)
{
    int blk = blockIdx.x;
    if (blk < 216) {
        int i = blk * 256 + threadIdx.x;
        const float* src; int ncol, local; const float* gv = nullptr;
        if (i < 27648)      { src = qkv_w;  ncol = 288; local = i; gv = ln1_g; }
        else if (i < 36864) { src = proj_w; ncol = 96;  local = i - 27648; }
        else if (i < 46080) { src = w1;     ncol = 96;  local = i - 36864; gv = ln2_g; }
        else                { src = w2;     ncol = 96;  local = i - 46080; }
        int j = local & 7, col = (local >> 3) & 15, ksub = (local >> 7) & 3;
        int rest = local >> 9;
        int kb = rest % 3, nt = rest / 3;
        int k = kb * 32 + ksub * 8 + j, n = nt * 16 + col;
        float v = src[k * ncol + n];
        if (gv) v *= gv[k];
        ws[i] = (_Float16)v;
    } else if (blk == 216) {
        int n = threadIdx.x;                   // qkv bias cols 0..255
        float s = qkv_b[n];
        for (int k = 0; k < 96; ++k) s += ln1_b[k] * qkv_w[k * 288 + n];
        bias_out[n] = s;
    } else {
        int t = threadIdx.x;
        if (t < 32) {                          // qkv bias cols 256..287
            int n = 256 + t;
            float s = qkv_b[n];
            for (int k = 0; k < 96; ++k) s += ln1_b[k] * qkv_w[k * 288 + n];
            bias_out[n] = s;
        } else if (t < 128) {                  // mlp bias1 cols
            int n = t - 32;
            float s = mlp_b1[n];
            for (int k = 0; k < 96; ++k) s += ln2_b[k] * w1[k * 96 + n];
            bias_out[288 + n] = s;
        }
    }
}

// ---------------------------------------------------------------------------
// Fully fused Swin block. One block per (batch,window); TWO barriers;
// 36.9 KB LDS -> 4 blocks/CU. LDS planes aliased over time:
//   region A [0,12288):      XLN -> Qu -> Pu(lo) -> Ou -> XT
//   region B [12288,24576):  Ku -> Pu(hi) -> YT
//   region V [24576,36864):  Vu (pad planes zeroed by wave 3 at entry)
// Residual x loads are issued AFTER B3 (no intervening barrier before use,
// so the compiler's vmcnt(0)-before-barrier drain cannot serialize them).
// ---------------------------------------------------------------------------
__global__ __launch_bounds__(256, 4) void attn_k9(
    const float* __restrict__ x,
    const float* __restrict__ attn_bias,
    const float* __restrict__ proj_b,
    const float* __restrict__ mlp_b2,
    const _Float16* __restrict__ wpack,
    const float* __restrict__ biasf,   // [0,288) qkv folded, [288,384) mlp1 folded
    float* __restrict__ out)
{
    __shared__ __align__(16) char smem[36864];

    _Float16*  XLN = (_Float16*)smem;
    _Float16*  Qu  = (_Float16*)smem;
    _Float16*  Ku  = (_Float16*)(smem + 12288);
    _Float16*  Vu  = (_Float16*)(smem + 24576);
    _Float16*  Pu  = (_Float16*)smem;            // 24 planes spanning A+B
    _Float16*  Ou  = (_Float16*)smem;            // planes 0..11, own rows
    _Float16*  XT  = (_Float16*)smem;
    _Float16*  YT  = (_Float16*)(smem + 12288);

    const _Float16* qkvp  = wpack + QKVP_OFF;
    const _Float16* projp = wpack + PROJP_OFF;
    const _Float16* w1p   = wpack + W1P_OFF;
    const _Float16* w2p   = wpack + W2P_OFF;

    const int blk = blockIdx.x;
    const int b   = blk >> 6;
    const int w   = blk & 63;
    const int wh  = w >> 3, ww = w & 7;
    const int tid = threadIdx.x;
    const int wv  = tid >> 6, lane = tid & 63;
    const int l15 = lane & 15, l4 = lane >> 4;

    // ---- wave 3 zeroes V pad planes (token groups 6,7 per head) ----------
    if (wv == 3) {
        uint4* v4 = (uint4*)Vu;
        #pragma unroll
        for (int c = 0; c < 3; ++c)
            v4[(c * 8 + 6) * 32 + lane] = make_uint4(0, 0, 0, 0);
    }

    // ---- gather window (rolled) into registers: 4 threads/token ----------
    const int t_own = tid >> 2, part = tid & 3;
    const bool active = (tid < 196);
    float4 xq[6];
    float m = 0.f, rinv = 0.f;
    if (active) {
        int i = div7i(t_own), j = t_own - i * 7;
        int row = wh * WS + i + 3; if (row >= HH) row -= HH;
        int col = ww * WS + j + 3; if (col >= HH) col -= HH;
        const float* xp = &x[(((size_t)b * HW + row * HH + col) * 96) + part * 24];
        #pragma unroll
        for (int q = 0; q < 6; ++q) xq[q] = *(const float4*)&xp[q * 4];
        float sum = 0.f, sq = 0.f;
        #pragma unroll
        for (int q = 0; q < 6; ++q) {
            sum += xq[q].x + xq[q].y + xq[q].z + xq[q].w;
            sq  += xq[q].x * xq[q].x + xq[q].y * xq[q].y
                 + xq[q].z * xq[q].z + xq[q].w * xq[q].w;
        }
        sum += __shfl_xor(sum, 1); sq += __shfl_xor(sq, 1);
        sum += __shfl_xor(sum, 2); sq += __shfl_xor(sq, 2);
        m = sum * (1.0f / 96.0f);
        rinv = rsqrtf(sq * (1.0f / 96.0f) - m * m + 1e-5f);
    }

    // ---- normalize (affine folded into weights) -> XLN A-tiles -----------
    if (active) {
        #pragma unroll
        for (int cc = 0; cc < 3; ++cc) {
            half8 pk;
            #pragma unroll
            for (int j = 0; j < 8; ++j) {
                float v; int qi = cc * 2 + (j >> 2);
                if ((j & 3) == 0) v = xq[qi].x;
                else if ((j & 3) == 1) v = xq[qi].y;
                else if ((j & 3) == 2) v = xq[qi].z;
                else v = xq[qi].w;
                pk[j] = (_Float16)((v - m) * rinv);
            }
            *(half8*)&XLN[(part * 3 + cc) * 512 + t_own * 8] = pk;
        }
    }
    // NO barrier: QKV A-frags read own-stripe rows written by this wave.

    // ---- QKV GEMM: wave wv owns token tile mt=wv --------------------------
    {
        half8 a[3];
        #pragma unroll
        for (int kb = 0; kb < 3; ++kb)
            a[kb] = *(half8*)&XLN[(kb * 4 + l4) * 512 + (wv * 16 + l15) * 8];
        const int tok0 = wv * 16 + l4 * 4;

        // Q: nt 0..5 (unguarded: garbage rows replaced in softmax)
        #pragma unroll
        for (int nt = 0; nt < 6; ++nt) {
            f32x4 acc = {0.f, 0.f, 0.f, 0.f};
            #pragma unroll
            for (int kb = 0; kb < 3; ++kb) {
                half8 bw = *(const half8*)&qkvp[((nt * 3 + kb) * 4 + l4) * 128 + l15 * 8];
                acc = MFMA_F16(a[kb], bw, acc, 0, 0, 0);
            }
            int n = nt * 16 + l15;
            float bias = biasf[n];
            int h = n >> 5, d = n & 31;
            _Float16* qp = &Qu[(h * 4 + (d >> 3)) * 512 + tok0 * 8 + (d & 7)];
            #pragma unroll
            for (int r = 0; r < 4; ++r)
                qp[r * 8] = (_Float16)(acc[r] + bias);
        }
        // K: nt 6..11 (unguarded)
        #pragma unroll
        for (int nt = 6; nt < 12; ++nt) {
            f32x4 acc = {0.f, 0.f, 0.f, 0.f};
            #pragma unroll
            for (int kb = 0; kb < 3; ++kb) {
                half8 bw = *(const half8*)&qkvp[((nt * 3 + kb) * 4 + l4) * 128 + l15 * 8];
                acc = MFMA_F16(a[kb], bw, acc, 0, 0, 0);
            }
            int n = nt * 16 + l15;
            float bias = biasf[n];
            int n2 = n - 96, h = n2 >> 5, d = n2 & 31;
            _Float16* kp = &Ku[(h * 4 + (d >> 3)) * 512 + tok0 * 8 + (d & 7)];
            #pragma unroll
            for (int r = 0; r < 4; ++r)
                kp[r * 8] = (_Float16)(acc[r] + bias);
        }
        // V: nt 12..17 (guarded: pad rows must stay zero)
        #pragma unroll
        for (int nt = 12; nt < 18; ++nt) {
            f32x4 acc = {0.f, 0.f, 0.f, 0.f};
            #pragma unroll
            for (int kb = 0; kb < 3; ++kb) {
                half8 bw = *(const half8*)&qkvp[((nt * 3 + kb) * 4 + l4) * 128 + l15 * 8];
                acc = MFMA_F16(a[kb], bw, acc, 0, 0, 0);
            }
            int n = nt * 16 + l15;
            float bias = biasf[n];
            int n2 = n - 192, h = n2 >> 5, d = n2 & 31;
            #pragma unroll
            for (int r = 0; r < 4; ++r) {
                int tok = tok0 + r;
                if (tok < 49)
                    Vu[(h * 8 + (tok >> 3)) * 256 + d * 8 + (tok & 7)] = (_Float16)(acc[r] + bias);
            }
        }
    }
    __syncthreads();   // B2: K/V published for cross-wave reads

    // ---- scores: wave wv owns q-tile; all heads, K=32 single MFMA ---------
    f32x4 s[3][4];
    #pragma unroll
    for (int h = 0; h < 3; ++h) {
        half8 qf = *(half8*)&Qu[(h * 4 + l4) * 512 + (wv * 16 + l15) * 8];
        #pragma unroll
        for (int nt = 0; nt < 4; ++nt) {
            half8 kf = *(half8*)&Ku[(h * 4 + l4) * 512 + (nt * 16 + l15) * 8];
            f32x4 z = {0.f, 0.f, 0.f, 0.f};
            s[h][nt] = MFMA_F16(qf, kf, z, 0, 0, 0);
        }
    }
    __syncthreads();   // B3: Q,K dead for ALL waves -> P may overwrite A+B

    // ---- residual loads issued HERE (after the last barrier): latency
    //      hides under softmax VALU + PV MFMA, first use is in proj ---------
    size_t tbase[4]; bool tvalid[4];
    #pragma unroll
    for (int r = 0; r < 4; ++r) {
        int tok = wv * 16 + l4 * 4 + r;
        tvalid[r] = (tok < 49);
        int i = div7i(tok & 63), j = (tok & 63) - i * 7;
        int row = wh * WS + i + 3; if (row >= HH) row -= HH;
        int col = ww * WS + j + 3; if (col >= HH) col -= HH;
        tbase[r] = ((size_t)b * HW + row * HH + col) * 96;
    }
    float xr[6][4];
    #pragma unroll
    for (int nt = 0; nt < 6; ++nt) {
        int n = nt * 16 + l15;
        #pragma unroll
        for (int r = 0; r < 4; ++r)
            xr[nt][r] = tvalid[r] ? x[tbase[r] + n] : 0.f;
    }

    // ---- softmax (no max-subtraction; scores bounded) -> P tiles ----------
    {
        const float scale = 0.17677669529663687f;
        int qq[4]; bool qo[4]; int kc[4];
        bool keep[4][4];
        #pragma unroll
        for (int nt = 0; nt < 4; ++nt) {
            int k = nt * 16 + l15;
            kc[nt] = k < 49 ? k : 48;
        }
        #pragma unroll
        for (int r = 0; r < 4; ++r) {
            qq[r] = wv * 16 + l4 * 4 + r;
            qo[r] = qq[r] < 49;
            int qcl = qo[r] ? qq[r] : 48;
            int qi = div7i(qcl), qj = qcl - qi * 7;
            int lqr = lab9(wh * WS + qi), lqc = lab9(ww * WS + qj);
            #pragma unroll
            for (int nt = 0; nt < 4; ++nt) {
                int k = nt * 16 + l15;
                int ki = div7i(kc[nt]), kj = kc[nt] - ki * 7;
                keep[r][nt] = qo[r] && (k < 49) &&
                              (lqr == lab9(wh * WS + ki)) &&
                              (lqc == lab9(ww * WS + kj));
            }
        }
        #pragma unroll
        for (int h = 0; h < 3; ++h) {
            #pragma unroll
            for (int r = 0; r < 4; ++r) {
                int qcl = qo[r] ? qq[r] : 48;
                const float* bp = attn_bias + (h * 49 + qcl) * 49;
                float e[4], sum = 0.f;
                #pragma unroll
                for (int nt = 0; nt < 4; ++nt) {
                    float v = fmaf(s[h][nt][r], scale, bp[kc[nt]]);
                    e[nt] = keep[r][nt] ? __expf(v) : 0.f;
                    sum += e[nt];
                }
                sum += __shfl_xor(sum, 1);
                sum += __shfl_xor(sum, 2);
                sum += __shfl_xor(sum, 4);
                sum += __shfl_xor(sum, 8);
                float inv = qo[r] ? __builtin_amdgcn_rcpf(sum) : 0.f;
                #pragma unroll
                for (int nt = 0; nt < 4; ++nt) {
                    int k = nt * 16 + l15;
                    Pu[(h * 8 + (k >> 3)) * 512 + qq[r] * 8 + (k & 7)] =
                        (_Float16)(e[nt] * inv);
                }
            }
        }
    }
    // Everything below: wave-private own-stripe rows or read-only V.

    // ---- PV: O = P @ V (own q-stripe); O over own P rows ------------------
    #pragma unroll
    for (int h = 0; h < 3; ++h) {
        half8 pa0 = *(half8*)&Pu[(h * 8 + 0 + l4) * 512 + (wv * 16 + l15) * 8];
        half8 pa1 = *(half8*)&Pu[(h * 8 + 4 + l4) * 512 + (wv * 16 + l15) * 8];
        #pragma unroll
        for (int ntd = 0; ntd < 2; ++ntd) {
            f32x4 acc = {0.f, 0.f, 0.f, 0.f};
            half8 vb0 = *(half8*)&Vu[(h * 8 + 0 + l4) * 256 + (ntd * 16 + l15) * 8];
            acc = MFMA_F16(pa0, vb0, acc, 0, 0, 0);
            half8 vb1 = *(half8*)&Vu[(h * 8 + 4 + l4) * 256 + (ntd * 16 + l15) * 8];
            acc = MFMA_F16(pa1, vb1, acc, 0, 0, 0);
            int c = h * 32 + ntd * 16 + l15;
            #pragma unroll
            for (int r = 0; r < 4; ++r) {
                int tok = wv * 16 + l4 * 4 + r;
                Ou[(c >> 3) * 512 + tok * 8 + (c & 7)] = (_Float16)acc[r];
            }
        }
    }

    // ---- proj + residual into registers (x2 = x + attn_out) --------------
    float x2v[6][4];
    {
        half8 oa[3];
        #pragma unroll
        for (int kb = 0; kb < 3; ++kb)
            oa[kb] = *(half8*)&Ou[(kb * 4 + l4) * 512 + (wv * 16 + l15) * 8];
        for (int nt = 0; nt < 6; ++nt) {
            f32x4 acc = {0.f, 0.f, 0.f, 0.f};
            #pragma unroll
            for (int kb = 0; kb < 3; ++kb) {
                half8 bw = *(const half8*)&projp[((nt * 3 + kb) * 4 + l4) * 128 + l15 * 8];
                acc = MFMA_F16(oa[kb], bw, acc, 0, 0, 0);
            }
            int n = nt * 16 + l15;
            float pb = proj_b[n];
            #pragma unroll
            for (int r = 0; r < 4; ++r)
                x2v[nt][r] = tvalid[r] ? (xr[nt][r] + acc[r] + pb) : 0.f;
        }
    }

    // ---- LN2 in-register (affine folded into w1/bias1) --------------------
    float mu2[4], rs2[4];
    #pragma unroll
    for (int r = 0; r < 4; ++r) {
        float sum = 0.f, sq = 0.f;
        #pragma unroll
        for (int nt = 0; nt < 6; ++nt) { float v = x2v[nt][r]; sum += v; sq += v * v; }
        sum += __shfl_xor(sum, 1); sq += __shfl_xor(sq, 1);
        sum += __shfl_xor(sum, 2); sq += __shfl_xor(sq, 2);
        sum += __shfl_xor(sum, 4); sq += __shfl_xor(sq, 4);
        sum += __shfl_xor(sum, 8); sq += __shfl_xor(sq, 8);
        float mm = sum * (1.0f / 96.0f);
        mu2[r] = mm;
        rs2[r] = rsqrtf(sq * (1.0f / 96.0f) - mm * mm + 1e-5f);
    }

    // ---- x^ -> XT A-tiles (own rows; overwrites Ou after oa read) ---------
    #pragma unroll
    for (int nt = 0; nt < 6; ++nt) {
        int n = nt * 16 + l15;
        #pragma unroll
        for (int r = 0; r < 4; ++r) {
            int tok = wv * 16 + l4 * 4 + r;
            XT[(n >> 3) * 512 + tok * 8 + (n & 7)] =
                (_Float16)((x2v[nt][r] - mu2[r]) * rs2[r]);
        }
    }

    // ---- MLP GEMM1 + GELU -> YT tiles (own rows, over P-hi) ---------------
    {
        half8 a[3];
        #pragma unroll
        for (int kb = 0; kb < 3; ++kb)
            a[kb] = *(half8*)&XT[(kb * 4 + l4) * 512 + (wv * 16 + l15) * 8];
        for (int nt = 0; nt < 6; ++nt) {
            f32x4 acc = {0.f, 0.f, 0.f, 0.f};
            #pragma unroll
            for (int kb = 0; kb < 3; ++kb) {
                half8 bw = *(const half8*)&w1p[((nt * 3 + kb) * 4 + l4) * 128 + l15 * 8];
                acc = MFMA_F16(a[kb], bw, acc, 0, 0, 0);
            }
            int n = nt * 16 + l15;
            float bias = biasf[288 + n];
            #pragma unroll
            for (int r = 0; r < 4; ++r) {
                int tok = wv * 16 + l4 * 4 + r;
                float v = acc[r] + bias;
                // gelu(v) ~= v * sigmoid(v*(1.5957691 + 0.0713548*v^2))
                float v2 = v * v;
                float c2 = fmaf(v2, 0.0713548163f, 1.5957691216f);
                float z  = v * c2;
                float ex = __expf(-z);
                float y  = v * __builtin_amdgcn_rcpf(1.0f + ex);
                YT[(n >> 3) * 512 + tok * 8 + (n & 7)] = (_Float16)y;
            }
        }
    }

    // ---- MLP GEMM2 + final residual -> out --------------------------------
    {
        half8 a[3];
        #pragma unroll
        for (int kb = 0; kb < 3; ++kb)
            a[kb] = *(half8*)&YT[(kb * 4 + l4) * 512 + (wv * 16 + l15) * 8];
        for (int nt = 0; nt < 6; ++nt) {
            f32x4 acc = {0.f, 0.f, 0.f, 0.f};
            #pragma unroll
            for (int kb = 0; kb < 3; ++kb) {
                half8 bw = *(const half8*)&w2p[((nt * 3 + kb) * 4 + l4) * 128 + l15 * 8];
                acc = MFMA_F16(a[kb], bw, acc, 0, 0, 0);
            }
            int n = nt * 16 + l15;
            float bias = mlp_b2[n];
            #pragma unroll
            for (int r = 0; r < 4; ++r) {
                if (tvalid[r])
                    out[tbase[r] + n] = x2v[nt][r] + acc[r] + bias;
            }
        }
    }
}

extern "C" void kernel_launch(void* const* d_in, const int* in_sizes, int n_in,
                              void* d_out, int out_size, void* d_ws, size_t ws_size,
                              hipStream_t stream) {
    (void)in_sizes; (void)n_in; (void)ws_size; (void)out_size;
    const float* x         = (const float*)d_in[0];
    const float* qkv_w     = (const float*)d_in[1];
    const float* qkv_b     = (const float*)d_in[2];
    const float* attn_bias = (const float*)d_in[3];
    const float* proj_w    = (const float*)d_in[4];
    const float* proj_b    = (const float*)d_in[5];
    const float* ln1_g     = (const float*)d_in[6];
    const float* ln1_b     = (const float*)d_in[7];
    const float* ln2_g     = (const float*)d_in[8];
    const float* ln2_b     = (const float*)d_in[9];
    const float* mlp_w1    = (const float*)d_in[10];
    const float* mlp_b1    = (const float*)d_in[11];
    const float* mlp_w2    = (const float*)d_in[12];
    const float* mlp_b2    = (const float*)d_in[13];
    float* out = (float*)d_out;
    _Float16* wpack = (_Float16*)d_ws;
    float* biasf = (float*)((char*)d_ws + BIASF_BYTE);

    pack_w9<<<218, 256, 0, stream>>>(qkv_w, proj_w, mlp_w1, mlp_w2,
                                     ln1_g, ln1_b, ln2_g, ln2_b,
                                     qkv_b, mlp_b1, wpack, biasf);
    attn_k9<<<64 * 64, 256, 0, stream>>>(x, attn_bias, proj_b, mlp_b2,
                                         wpack, biasf, out);
}

// Round 13
// 135.921 us; speedup vs baseline: 1.0441x; 1.0352x over previous
//
#include <hip/hip_runtime.h>
#include <math.h>

typedef _Float16 half8 __attribute__((ext_vector_type(8)));
typedef float f32x4 __attribute__((ext_vector_type(4)));

#define MFMA_F16 __builtin_amdgcn_mfma_f32_16x16x32_f16

constexpr int WS = 7, HH = 56, HW = 3136;

// d_ws layout: fp16 tiles then f32 folded biases
constexpr int QKVP_OFF  = 0;       // 27648 fp16
constexpr int PROJP_OFF = 27648;   // 9216
constexpr int W1P_OFF   = 36864;   // 9216
constexpr int W2P_OFF   = 46080;   // 9216 -> 55296 fp16 = 110592 B
constexpr int BIASF_BYTE = 110592; // f32 [288 qkv' | 96 mlp1'] = 1536 B

__device__ __forceinline__ int labA(int v) { return v < 49 ? 0 : (v < 53 ? 1 : 2); }
__device__ __forceinline__ int div7a(int v) { return (v * 9363) >> 16; }  // valid 0..63

// ---------------------------------------------------------------------------
// Weight pre-pack with LN-affine folding:
//   qkv tiles row-scaled by ln1_g; w1 tiles row-scaled by ln2_g.
//   biasf[0..288) = qkv_b + ln1_b^T qkv_w ; [288..384) = mlp_b1 + ln2_b^T w1
// ---------------------------------------------------------------------------
__global__ __launch_bounds__(256) void pack_wA(
    const float* __restrict__ qkv_w, const float* __restrict__ proj_w,
    const float* __restrict__ w1, const float* __restrict__ w2,
    const float* __restrict__ ln1_g, const float* __restrict__ ln1_b,
    const float* __restrict__ ln2_g, const float* __restrict__ ln2_b,
    const float* __restrict__ qkv_b, const float* __restrict__ mlp_b1,
    _Float16* __restrict__ ws, float* __restrict__ bias_out)
{
    int blk = blockIdx.x;
    if (blk < 216) {
        int i = blk * 256 + threadIdx.x;
        const float* src; int ncol, local; const float* gv = nullptr;
        if (i < 27648)      { src = qkv_w;  ncol = 288; local = i; gv = ln1_g; }
        else if (i < 36864) { src = proj_w; ncol = 96;  local = i - 27648; }
        else if (i < 46080) { src = w1;     ncol = 96;  local = i - 36864; gv = ln2_g; }
        else                { src = w2;     ncol = 96;  local = i - 46080; }
        int j = local & 7, col = (local >> 3) & 15, ksub = (local >> 7) & 3;
        int rest = local >> 9;
        int kb = rest % 3, nt = rest / 3;
        int k = kb * 32 + ksub * 8 + j, n = nt * 16 + col;
        float v = src[k * ncol + n];
        if (gv) v *= gv[k];
        ws[i] = (_Float16)v;
    } else if (blk == 216) {
        int n = threadIdx.x;                   // qkv bias cols 0..255
        float s = qkv_b[n];
        for (int k = 0; k < 96; ++k) s += ln1_b[k] * qkv_w[k * 288 + n];
        bias_out[n] = s;
    } else {
        int t = threadIdx.x;
        if (t < 32) {                          // qkv bias cols 256..287
            int n = 256 + t;
            float s = qkv_b[n];
            for (int k = 0; k < 96; ++k) s += ln1_b[k] * qkv_w[k * 288 + n];
            bias_out[n] = s;
        } else if (t < 128) {                  // mlp bias1 cols
            int n = t - 32;
            float s = mlp_b1[n];
            for (int k = 0; k < 96; ++k) s += ln2_b[k] * w1[k * 96 + n];
            bias_out[288 + n] = s;
        }
    }
}

// ---------------------------------------------------------------------------
// Fully fused Swin block — EXACT R9 (131 us) structure: 3 barriers,
// all-thread V zeroing, residual x loaded inline in proj. Only change:
// LN affine folded into packed weights/biases (biasf).
// LDS planes aliased over time:
//   region A [0,12288):      XLN -> Qu -> Pu(lo) -> Ou -> XT
//   region B [12288,24576):  Ku -> Pu(hi) -> YT
//   region V [24576,36864):  Vu
// ---------------------------------------------------------------------------
__global__ __launch_bounds__(256, 4) void attn_kA(
    const float* __restrict__ x,
    const float* __restrict__ attn_bias,
    const float* __restrict__ proj_b,
    const float* __restrict__ mlp_b2,
    const _Float16* __restrict__ wpack,
    const float* __restrict__ biasf,
    float* __restrict__ out)
{
    __shared__ __align__(16) char smem[36864];

    _Float16*  XLN = (_Float16*)smem;
    _Float16*  Qu  = (_Float16*)smem;
    _Float16*  Ku  = (_Float16*)(smem + 12288);
    _Float16*  Vu  = (_Float16*)(smem + 24576);
    _Float16*  Pu  = (_Float16*)smem;            // 24 planes spanning A+B
    _Float16*  Ou  = (_Float16*)smem;            // planes 0..11, own rows
    _Float16*  XT  = (_Float16*)smem;
    _Float16*  YT  = (_Float16*)(smem + 12288);

    const _Float16* qkvp  = wpack + QKVP_OFF;
    const _Float16* projp = wpack + PROJP_OFF;
    const _Float16* w1p   = wpack + W1P_OFF;
    const _Float16* w2p   = wpack + W2P_OFF;

    const int blk = blockIdx.x;
    const int b   = blk >> 6;
    const int w   = blk & 63;
    const int wh  = w >> 3, ww = w & 7;
    const int tid = threadIdx.x;
    const int wv  = tid >> 6, lane = tid & 63;
    const int l15 = lane & 15, l4 = lane >> 4;

    // ---- zero V pad region (all threads, as in R9) ----
    for (int idx = tid; idx < 768; idx += 256)
        ((uint4*)Vu)[idx] = make_uint4(0, 0, 0, 0);

    // ---- gather window (rolled) into registers: 4 threads/token ----------
    const int t_own = tid >> 2, part = tid & 3;
    const bool active = (tid < 196);
    float4 xq[6];
    float m = 0.f, rinv = 0.f;
    if (active) {
        int i = div7a(t_own), j = t_own - i * 7;
        int row = wh * WS + i + 3; if (row >= HH) row -= HH;
        int col = ww * WS + j + 3; if (col >= HH) col -= HH;
        const float* xp = &x[(((size_t)b * HW + row * HH + col) * 96) + part * 24];
        #pragma unroll
        for (int q = 0; q < 6; ++q) xq[q] = *(const float4*)&xp[q * 4];
        float sum = 0.f, sq = 0.f;
        #pragma unroll
        for (int q = 0; q < 6; ++q) {
            sum += xq[q].x + xq[q].y + xq[q].z + xq[q].w;
            sq  += xq[q].x * xq[q].x + xq[q].y * xq[q].y
                 + xq[q].z * xq[q].z + xq[q].w * xq[q].w;
        }
        sum += __shfl_xor(sum, 1); sq += __shfl_xor(sq, 1);
        sum += __shfl_xor(sum, 2); sq += __shfl_xor(sq, 2);
        m = sum * (1.0f / 96.0f);
        rinv = rsqrtf(sq * (1.0f / 96.0f) - m * m + 1e-5f);
    }
    __syncthreads();   // B1: V zeroed

    // ---- normalize (affine folded into weights) -> XLN A-tiles -----------
    if (active) {
        #pragma unroll
        for (int cc = 0; cc < 3; ++cc) {
            half8 pk;
            #pragma unroll
            for (int j = 0; j < 8; ++j) {
                float v; int qi = cc * 2 + (j >> 2);
                if ((j & 3) == 0) v = xq[qi].x;
                else if ((j & 3) == 1) v = xq[qi].y;
                else if ((j & 3) == 2) v = xq[qi].z;
                else v = xq[qi].w;
                pk[j] = (_Float16)((v - m) * rinv);
            }
            *(half8*)&XLN[(part * 3 + cc) * 512 + t_own * 8] = pk;
        }
    }
    // NO barrier: QKV A-frags read own-stripe rows written by this wave.

    // ---- QKV GEMM: wave wv owns token tile mt=wv --------------------------
    {
        half8 a[3];
        #pragma unroll
        for (int kb = 0; kb < 3; ++kb)
            a[kb] = *(half8*)&XLN[(kb * 4 + l4) * 512 + (wv * 16 + l15) * 8];
        const int tok0 = wv * 16 + l4 * 4;

        // Q: nt 0..5 (unguarded: garbage rows replaced in softmax)
        #pragma unroll
        for (int nt = 0; nt < 6; ++nt) {
            f32x4 acc = {0.f, 0.f, 0.f, 0.f};
            #pragma unroll
            for (int kb = 0; kb < 3; ++kb) {
                half8 bw = *(const half8*)&qkvp[((nt * 3 + kb) * 4 + l4) * 128 + l15 * 8];
                acc = MFMA_F16(a[kb], bw, acc, 0, 0, 0);
            }
            int n = nt * 16 + l15;
            float bias = biasf[n];
            int h = n >> 5, d = n & 31;
            _Float16* qp = &Qu[(h * 4 + (d >> 3)) * 512 + tok0 * 8 + (d & 7)];
            #pragma unroll
            for (int r = 0; r < 4; ++r)
                qp[r * 8] = (_Float16)(acc[r] + bias);
        }
        // K: nt 6..11 (unguarded)
        #pragma unroll
        for (int nt = 6; nt < 12; ++nt) {
            f32x4 acc = {0.f, 0.f, 0.f, 0.f};
            #pragma unroll
            for (int kb = 0; kb < 3; ++kb) {
                half8 bw = *(const half8*)&qkvp[((nt * 3 + kb) * 4 + l4) * 128 + l15 * 8];
                acc = MFMA_F16(a[kb], bw, acc, 0, 0, 0);
            }
            int n = nt * 16 + l15;
            float bias = biasf[n];
            int n2 = n - 96, h = n2 >> 5, d = n2 & 31;
            _Float16* kp = &Ku[(h * 4 + (d >> 3)) * 512 + tok0 * 8 + (d & 7)];
            #pragma unroll
            for (int r = 0; r < 4; ++r)
                kp[r * 8] = (_Float16)(acc[r] + bias);
        }
        // V: nt 12..17 (guarded: pad rows must stay zero)
        #pragma unroll
        for (int nt = 12; nt < 18; ++nt) {
            f32x4 acc = {0.f, 0.f, 0.f, 0.f};
            #pragma unroll
            for (int kb = 0; kb < 3; ++kb) {
                half8 bw = *(const half8*)&qkvp[((nt * 3 + kb) * 4 + l4) * 128 + l15 * 8];
                acc = MFMA_F16(a[kb], bw, acc, 0, 0, 0);
            }
            int n = nt * 16 + l15;
            float bias = biasf[n];
            int n2 = n - 192, h = n2 >> 5, d = n2 & 31;
            #pragma unroll
            for (int r = 0; r < 4; ++r) {
                int tok = tok0 + r;
                if (tok < 49)
                    Vu[(h * 8 + (tok >> 3)) * 256 + d * 8 + (tok & 7)] = (_Float16)(acc[r] + bias);
            }
        }
    }
    __syncthreads();   // B2: K/V published for cross-wave reads

    // ---- scores: wave wv owns q-tile; all heads, K=32 single MFMA ---------
    f32x4 s[3][4];
    #pragma unroll
    for (int h = 0; h < 3; ++h) {
        half8 qf = *(half8*)&Qu[(h * 4 + l4) * 512 + (wv * 16 + l15) * 8];
        #pragma unroll
        for (int nt = 0; nt < 4; ++nt) {
            half8 kf = *(half8*)&Ku[(h * 4 + l4) * 512 + (nt * 16 + l15) * 8];
            f32x4 z = {0.f, 0.f, 0.f, 0.f};
            s[h][nt] = MFMA_F16(qf, kf, z, 0, 0, 0);
        }
    }
    __syncthreads();   // B3: Q,K dead for ALL waves -> P may overwrite A+B

    // ---- softmax (no max-subtraction; scores bounded) -> P tiles ----------
    {
        const float scale = 0.17677669529663687f;
        int qq[4]; bool qo[4]; int kc[4];
        bool keep[4][4];
        #pragma unroll
        for (int nt = 0; nt < 4; ++nt) {
            int k = nt * 16 + l15;
            kc[nt] = k < 49 ? k : 48;
        }
        #pragma unroll
        for (int r = 0; r < 4; ++r) {
            qq[r] = wv * 16 + l4 * 4 + r;
            qo[r] = qq[r] < 49;
            int qcl = qo[r] ? qq[r] : 48;
            int qi = div7a(qcl), qj = qcl - qi * 7;
            int lqr = labA(wh * WS + qi), lqc = labA(ww * WS + qj);
            #pragma unroll
            for (int nt = 0; nt < 4; ++nt) {
                int k = nt * 16 + l15;
                int ki = div7a(kc[nt]), kj = kc[nt] - ki * 7;
                keep[r][nt] = qo[r] && (k < 49) &&
                              (lqr == labA(wh * WS + ki)) &&
                              (lqc == labA(ww * WS + kj));
            }
        }
        #pragma unroll
        for (int h = 0; h < 3; ++h) {
            #pragma unroll
            for (int r = 0; r < 4; ++r) {
                int qcl = qo[r] ? qq[r] : 48;
                const float* bp = attn_bias + (h * 49 + qcl) * 49;
                float e[4], sum = 0.f;
                #pragma unroll
                for (int nt = 0; nt < 4; ++nt) {
                    float v = fmaf(s[h][nt][r], scale, bp[kc[nt]]);
                    e[nt] = keep[r][nt] ? __expf(v) : 0.f;
                    sum += e[nt];
                }
                sum += __shfl_xor(sum, 1);
                sum += __shfl_xor(sum, 2);
                sum += __shfl_xor(sum, 4);
                sum += __shfl_xor(sum, 8);
                float inv = qo[r] ? __builtin_amdgcn_rcpf(sum) : 0.f;
                #pragma unroll
                for (int nt = 0; nt < 4; ++nt) {
                    int k = nt * 16 + l15;
                    Pu[(h * 8 + (k >> 3)) * 512 + qq[r] * 8 + (k & 7)] =
                        (_Float16)(e[nt] * inv);
                }
            }
        }
    }
    // Everything below: wave-private own-stripe rows or read-only V.

    // ---- PV: O = P @ V (own q-stripe); O over own P rows ------------------
    #pragma unroll
    for (int h = 0; h < 3; ++h) {
        half8 pa0 = *(half8*)&Pu[(h * 8 + 0 + l4) * 512 + (wv * 16 + l15) * 8];
        half8 pa1 = *(half8*)&Pu[(h * 8 + 4 + l4) * 512 + (wv * 16 + l15) * 8];
        #pragma unroll
        for (int ntd = 0; ntd < 2; ++ntd) {
            f32x4 acc = {0.f, 0.f, 0.f, 0.f};
            half8 vb0 = *(half8*)&Vu[(h * 8 + 0 + l4) * 256 + (ntd * 16 + l15) * 8];
            acc = MFMA_F16(pa0, vb0, acc, 0, 0, 0);
            half8 vb1 = *(half8*)&Vu[(h * 8 + 4 + l4) * 256 + (ntd * 16 + l15) * 8];
            acc = MFMA_F16(pa1, vb1, acc, 0, 0, 0);
            int c = h * 32 + ntd * 16 + l15;
            #pragma unroll
            for (int r = 0; r < 4; ++r) {
                int tok = wv * 16 + l4 * 4 + r;
                Ou[(c >> 3) * 512 + tok * 8 + (c & 7)] = (_Float16)acc[r];
            }
        }
    }

    // ---- proj + residual (x loaded inline, as R9) -> registers ------------
    float x2v[6][4];
    size_t tbase[4]; bool tvalid[4];
    {
        half8 oa[3];
        #pragma unroll
        for (int kb = 0; kb < 3; ++kb)
            oa[kb] = *(half8*)&Ou[(kb * 4 + l4) * 512 + (wv * 16 + l15) * 8];

        #pragma unroll
        for (int r = 0; r < 4; ++r) {
            int tok = wv * 16 + l4 * 4 + r;
            tvalid[r] = (tok < 49);
            int i = div7a(tok & 63), j = (tok & 63) - i * 7;
            int row = wh * WS + i + 3; if (row >= HH) row -= HH;
            int col = ww * WS + j + 3; if (col >= HH) col -= HH;
            tbase[r] = ((size_t)b * HW + row * HH + col) * 96;
        }
        for (int nt = 0; nt < 6; ++nt) {
            f32x4 acc = {0.f, 0.f, 0.f, 0.f};
            #pragma unroll
            for (int kb = 0; kb < 3; ++kb) {
                half8 bw = *(const half8*)&projp[((nt * 3 + kb) * 4 + l4) * 128 + l15 * 8];
                acc = MFMA_F16(oa[kb], bw, acc, 0, 0, 0);
            }
            int n = nt * 16 + l15;
            float pb = proj_b[n];
            #pragma unroll
            for (int r = 0; r < 4; ++r)
                x2v[nt][r] = tvalid[r] ? (x[tbase[r] + n] + acc[r] + pb) : 0.f;
        }
    }

    // ---- LN2 in-register (affine folded into w1/bias1) --------------------
    float mu2[4], rs2[4];
    #pragma unroll
    for (int r = 0; r < 4; ++r) {
        float sum = 0.f, sq = 0.f;
        #pragma unroll
        for (int nt = 0; nt < 6; ++nt) { float v = x2v[nt][r]; sum += v; sq += v * v; }
        sum += __shfl_xor(sum, 1); sq += __shfl_xor(sq, 1);
        sum += __shfl_xor(sum, 2); sq += __shfl_xor(sq, 2);
        sum += __shfl_xor(sum, 4); sq += __shfl_xor(sq, 4);
        sum += __shfl_xor(sum, 8); sq += __shfl_xor(sq, 8);
        float mm = sum * (1.0f / 96.0f);
        mu2[r] = mm;
        rs2[r] = rsqrtf(sq * (1.0f / 96.0f) - mm * mm + 1e-5f);
    }

    // ---- x^ -> XT A-tiles (own rows; overwrites Ou after oa read) ---------
    #pragma unroll
    for (int nt = 0; nt < 6; ++nt) {
        int n = nt * 16 + l15;
        #pragma unroll
        for (int r = 0; r < 4; ++r) {
            int tok = wv * 16 + l4 * 4 + r;
            XT[(n >> 3) * 512 + tok * 8 + (n & 7)] =
                (_Float16)((x2v[nt][r] - mu2[r]) * rs2[r]);
        }
    }

    // ---- MLP GEMM1 + GELU -> YT tiles (own rows) --------------------------
    {
        half8 a[3];
        #pragma unroll
        for (int kb = 0; kb < 3; ++kb)
            a[kb] = *(half8*)&XT[(kb * 4 + l4) * 512 + (wv * 16 + l15) * 8];
        for (int nt = 0; nt < 6; ++nt) {
            f32x4 acc = {0.f, 0.f, 0.f, 0.f};
            #pragma unroll
            for (int kb = 0; kb < 3; ++kb) {
                half8 bw = *(const half8*)&w1p[((nt * 3 + kb) * 4 + l4) * 128 + l15 * 8];
                acc = MFMA_F16(a[kb], bw, acc, 0, 0, 0);
            }
            int n = nt * 16 + l15;
            float bias = biasf[288 + n];
            #pragma unroll
            for (int r = 0; r < 4; ++r) {
                int tok = wv * 16 + l4 * 4 + r;
                float v = acc[r] + bias;
                // gelu(v) ~= v * sigmoid(v*(1.5957691 + 0.0713548*v^2))
                float v2 = v * v;
                float c2 = fmaf(v2, 0.0713548163f, 1.5957691216f);
                float z  = v * c2;
                float ex = __expf(-z);
                float y  = v * __builtin_amdgcn_rcpf(1.0f + ex);
                YT[(n >> 3) * 512 + tok * 8 + (n & 7)] = (_Float16)y;
            }
        }
    }

    // ---- MLP GEMM2 + final residual -> out --------------------------------
    {
        half8 a[3];
        #pragma unroll
        for (int kb = 0; kb < 3; ++kb)
            a[kb] = *(half8*)&YT[(kb * 4 + l4) * 512 + (wv * 16 + l15) * 8];
        for (int nt = 0; nt < 6; ++nt) {
            f32x4 acc = {0.f, 0.f, 0.f, 0.f};
            #pragma unroll
            for (int kb = 0; kb < 3; ++kb) {
                half8 bw = *(const half8*)&w2p[((nt * 3 + kb) * 4 + l4) * 128 + l15 * 8];
                acc = MFMA_F16(a[kb], bw, acc, 0, 0, 0);
            }
            int n = nt * 16 + l15;
            float bias = mlp_b2[n];
            #pragma unroll
            for (int r = 0; r < 4; ++r) {
                if (tvalid[r])
                    out[tbase[r] + n] = x2v[nt][r] + acc[r] + bias;
            }
        }
    }
}

extern "C" void kernel_launch(void* const* d_in, const int* in_sizes, int n_in,
                              void* d_out, int out_size, void* d_ws, size_t ws_size,
                              hipStream_t stream) {
    (void)in_sizes; (void)n_in; (void)ws_size; (void)out_size;
    const float* x         = (const float*)d_in[0];
    const float* qkv_w     = (const float*)d_in[1];
    const float* qkv_b     = (const float*)d_in[2];
    const float* attn_bias = (const float*)d_in[3];
    const float* proj_w    = (const float*)d_in[4];
    const float* proj_b    = (const float*)d_in[5];
    const float* ln1_g     = (const float*)d_in[6];
    const float* ln1_b     = (const float*)d_in[7];
    const float* ln2_g     = (const float*)d_in[8];
    const float* ln2_b     = (const float*)d_in[9];
    const float* mlp_w1    = (const float*)d_in[10];
    const float* mlp_b1    = (const float*)d_in[11];
    const float* mlp_w2    = (const float*)d_in[12];
    const float* mlp_b2    = (const float*)d_in[13];
    float* out = (float*)d_out;
    _Float16* wpack = (_Float16*)d_ws;
    float* biasf = (float*)((char*)d_ws + BIASF_BYTE);

    pack_wA<<<218, 256, 0, stream>>>(qkv_w, proj_w, mlp_w1, mlp_w2,
                                     ln1_g, ln1_b, ln2_g, ln2_b,
                                     qkv_b, mlp_b1, wpack, biasf);
    attn_kA<<<64 * 64, 256, 0, stream>>>(x, attn_bias, proj_b, mlp_b2,
                                         wpack, biasf, out);
}

// Round 14
// 128.074 us; speedup vs baseline: 1.1081x; 1.0613x over previous
//
#include <hip/hip_runtime.h>
#include <math.h>

typedef _Float16 half8 __attribute__((ext_vector_type(8)));
typedef _Float16 half4 __attribute__((ext_vector_type(4)));
typedef float f32x4 __attribute__((ext_vector_type(4)));

#define MFMA_F16 __builtin_amdgcn_mfma_f32_16x16x32_f16

constexpr int WS = 7, HH = 56, HW = 3136;

// d_ws layout: fp16 tiles then f32 folded biases
constexpr int QKVP_OFF  = 0;       // 27648 fp16
constexpr int PROJP_OFF = 27648;   // 9216
constexpr int W1P_OFF   = 36864;   // 9216
constexpr int W2P_OFF   = 46080;   // 9216 -> 55296 fp16 = 110592 B
constexpr int BIASF_BYTE = 110592; // f32 [288 qkv' | 96 mlp1'] = 1536 B

__device__ __forceinline__ int labB(int v) { return v < 49 ? 0 : (v < 53 ? 1 : 2); }
__device__ __forceinline__ int div7b(int v) { return (v * 9363) >> 16; }  // valid 0..63

// ---------------------------------------------------------------------------
// Weight pre-pack with LN-affine folding (unchanged from R12).
// ---------------------------------------------------------------------------
__global__ __launch_bounds__(256) void pack_wB(
    const float* __restrict__ qkv_w, const float* __restrict__ proj_w,
    const float* __restrict__ w1, const float* __restrict__ w2,
    const float* __restrict__ ln1_g, const float* __restrict__ ln1_b,
    const float* __restrict__ ln2_g, const float* __restrict__ ln2_b,
    const float* __restrict__ qkv_b, const float* __restrict__ mlp_b1,
    _Float16* __restrict__ ws, float* __restrict__ bias_out)
{
    int blk = blockIdx.x;
    if (blk < 216) {
        int i = blk * 256 + threadIdx.x;
        const float* src; int ncol, local; const float* gv = nullptr;
        if (i < 27648)      { src = qkv_w;  ncol = 288; local = i; gv = ln1_g; }
        else if (i < 36864) { src = proj_w; ncol = 96;  local = i - 27648; }
        else if (i < 46080) { src = w1;     ncol = 96;  local = i - 36864; gv = ln2_g; }
        else                { src = w2;     ncol = 96;  local = i - 46080; }
        int j = local & 7, col = (local >> 3) & 15, ksub = (local >> 7) & 3;
        int rest = local >> 9;
        int kb = rest % 3, nt = rest / 3;
        int k = kb * 32 + ksub * 8 + j, n = nt * 16 + col;
        float v = src[k * ncol + n];
        if (gv) v *= gv[k];
        ws[i] = (_Float16)v;
    } else if (blk == 216) {
        int n = threadIdx.x;
        float s = qkv_b[n];
        for (int k = 0; k < 96; ++k) s += ln1_b[k] * qkv_w[k * 288 + n];
        bias_out[n] = s;
    } else {
        int t = threadIdx.x;
        if (t < 32) {
            int n = 256 + t;
            float s = qkv_b[n];
            for (int k = 0; k < 96; ++k) s += ln1_b[k] * qkv_w[k * 288 + n];
            bias_out[n] = s;
        } else if (t < 128) {
            int n = t - 32;
            float s = mlp_b1[n];
            for (int k = 0; k < 96; ++k) s += ln2_b[k] * w1[k * 96 + n];
            bias_out[288 + n] = s;
        }
    }
}

// ---------------------------------------------------------------------------
// Fully fused Swin block, ALL GEMMS TRANSPOSED (A=weights/V^T/K, B=activation
// tiles). D layout per lane: col=l15 -> one token, rows l4*4+r -> 4 consecutive
// channels => b64 LDS epilogue stores, float4 global loads/stores, uniform
// per-thread token guards, short shuffle reductions.
// One block per (batch,window); 3 barriers; 36.9 KB LDS -> 4 blocks/CU.
// LDS planes aliased over time (row-disjoint across waves where unbarriered):
//   region A [0,12288):      XLN -> Qu -> Pu(lo) -> Ou -> XT
//   region B [12288,24576):  Ku -> Pu(hi) -> YT
//   region V [24576,36864):  Vu
// ---------------------------------------------------------------------------
__global__ __launch_bounds__(256, 4) void attn_kB(
    const float* __restrict__ x,
    const float* __restrict__ attn_bias,
    const float* __restrict__ proj_b,
    const float* __restrict__ mlp_b2,
    const _Float16* __restrict__ wpack,
    const float* __restrict__ biasf,
    float* __restrict__ out)
{
    __shared__ __align__(16) char smem[36864];

    _Float16*  XLN = (_Float16*)smem;
    _Float16*  Qu  = (_Float16*)smem;
    _Float16*  Ku  = (_Float16*)(smem + 12288);
    _Float16*  Vu  = (_Float16*)(smem + 24576);
    _Float16*  Pu  = (_Float16*)smem;            // 24 planes spanning A+B
    _Float16*  Ou  = (_Float16*)smem;            // planes 0..11
    _Float16*  XT  = (_Float16*)smem;
    _Float16*  YT  = (_Float16*)(smem + 12288);

    const _Float16* qkvp  = wpack + QKVP_OFF;
    const _Float16* projp = wpack + PROJP_OFF;
    const _Float16* w1p   = wpack + W1P_OFF;
    const _Float16* w2p   = wpack + W2P_OFF;

    const int blk = blockIdx.x;
    const int b   = blk >> 6;
    const int w   = blk & 63;
    const int wh  = w >> 3, ww = w & 7;
    const int tid = threadIdx.x;
    const int wv  = tid >> 6, lane = tid & 63;
    const int l15 = lane & 15, l4 = lane >> 4;

    const int  tcol   = wv * 16 + l15;     // this thread's token (D column)
    const bool tok_ok = tcol < 49;

    // ---- zero V pad region ----
    for (int idx = tid; idx < 768; idx += 256)
        ((uint4*)Vu)[idx] = make_uint4(0, 0, 0, 0);

    // ---- gather window (rolled) into registers: 4 threads/token ----------
    const int t_own = tid >> 2, part = tid & 3;
    const bool active = (tid < 196);
    float4 xq[6];
    float m = 0.f, rinv = 0.f;
    if (active) {
        int i = div7b(t_own), j = t_own - i * 7;
        int row = wh * WS + i + 3; if (row >= HH) row -= HH;
        int col = ww * WS + j + 3; if (col >= HH) col -= HH;
        const float* xp = &x[(((size_t)b * HW + row * HH + col) * 96) + part * 24];
        #pragma unroll
        for (int q = 0; q < 6; ++q) xq[q] = *(const float4*)&xp[q * 4];
        float sum = 0.f, sq = 0.f;
        #pragma unroll
        for (int q = 0; q < 6; ++q) {
            sum += xq[q].x + xq[q].y + xq[q].z + xq[q].w;
            sq  += xq[q].x * xq[q].x + xq[q].y * xq[q].y
                 + xq[q].z * xq[q].z + xq[q].w * xq[q].w;
        }
        sum += __shfl_xor(sum, 1); sq += __shfl_xor(sq, 1);
        sum += __shfl_xor(sum, 2); sq += __shfl_xor(sq, 2);
        m = sum * (1.0f / 96.0f);
        rinv = rsqrtf(sq * (1.0f / 96.0f) - m * m + 1e-5f);
    }
    __syncthreads();   // B1: V zeroed

    // ---- normalize (affine folded) -> XLN tiles (own-wave rows) -----------
    if (active) {
        #pragma unroll
        for (int cc = 0; cc < 3; ++cc) {
            half8 pk;
            #pragma unroll
            for (int j = 0; j < 8; ++j) {
                float v; int qi = cc * 2 + (j >> 2);
                if ((j & 3) == 0) v = xq[qi].x;
                else if ((j & 3) == 1) v = xq[qi].y;
                else if ((j & 3) == 2) v = xq[qi].z;
                else v = xq[qi].w;
                pk[j] = (_Float16)((v - m) * rinv);
            }
            *(half8*)&XLN[(part * 3 + cc) * 512 + t_own * 8] = pk;
        }
    }
    // NO barrier: B-frag cols below are own-wave tokens.

    // ---- QKV GEMM (transposed: A=W^T, B=XLN; D rows=channels, col=token) --
    {
        half8 bx[3];
        #pragma unroll
        for (int kb = 0; kb < 3; ++kb)
            bx[kb] = *(half8*)&XLN[(kb * 4 + l4) * 512 + tcol * 8];

        // Q: nt 0..5 -> b64 stores (pad-token cols garbage, masked later)
        #pragma unroll
        for (int nt = 0; nt < 6; ++nt) {
            f32x4 acc = {0.f, 0.f, 0.f, 0.f};
            #pragma unroll
            for (int kb = 0; kb < 3; ++kb) {
                half8 bw = *(const half8*)&qkvp[((nt * 3 + kb) * 4 + l4) * 128 + l15 * 8];
                acc = MFMA_F16(bw, bx[kb], acc, 0, 0, 0);
            }
            int n0 = nt * 16 + l4 * 4;
            f32x4 b4 = *(const f32x4*)&biasf[n0];
            int h = n0 >> 5, d0 = n0 & 31;
            half4 st;
            #pragma unroll
            for (int r = 0; r < 4; ++r) st[r] = (_Float16)(acc[r] + b4[r]);
            *(half4*)&Qu[(h * 4 + (d0 >> 3)) * 512 + tcol * 8 + (d0 & 7)] = st;
        }
        // K: nt 6..11
        #pragma unroll
        for (int nt = 6; nt < 12; ++nt) {
            f32x4 acc = {0.f, 0.f, 0.f, 0.f};
            #pragma unroll
            for (int kb = 0; kb < 3; ++kb) {
                half8 bw = *(const half8*)&qkvp[((nt * 3 + kb) * 4 + l4) * 128 + l15 * 8];
                acc = MFMA_F16(bw, bx[kb], acc, 0, 0, 0);
            }
            int n0 = nt * 16 + l4 * 4;
            f32x4 b4 = *(const f32x4*)&biasf[n0];
            int n2 = n0 - 96, h = n2 >> 5, d0 = n2 & 31;
            half4 st;
            #pragma unroll
            for (int r = 0; r < 4; ++r) st[r] = (_Float16)(acc[r] + b4[r]);
            *(half4*)&Ku[(h * 4 + (d0 >> 3)) * 512 + tcol * 8 + (d0 & 7)] = st;
        }
        // V: nt 12..17 (uniform per-thread guard; pad rows stay zero)
        #pragma unroll
        for (int nt = 12; nt < 18; ++nt) {
            f32x4 acc = {0.f, 0.f, 0.f, 0.f};
            #pragma unroll
            for (int kb = 0; kb < 3; ++kb) {
                half8 bw = *(const half8*)&qkvp[((nt * 3 + kb) * 4 + l4) * 128 + l15 * 8];
                acc = MFMA_F16(bw, bx[kb], acc, 0, 0, 0);
            }
            int n0 = nt * 16 + l4 * 4;
            f32x4 b4 = *(const f32x4*)&biasf[n0];
            int n2 = n0 - 192, h = n2 >> 5, d0 = n2 & 31;
            if (tok_ok) {
                int vb = (h * 8 + (tcol >> 3)) * 256 + d0 * 8 + (tcol & 7);
                #pragma unroll
                for (int r = 0; r < 4; ++r)
                    Vu[vb + r * 8] = (_Float16)(acc[r] + b4[r]);
            }
        }
    }
    __syncthreads();   // B2: K/V published for cross-wave reads

    // ---- scores (transposed: A=K, B=Q): D rows=k, col=q=tcol --------------
    f32x4 s[3][4];
    #pragma unroll
    for (int h = 0; h < 3; ++h) {
        half8 qf = *(half8*)&Qu[(h * 4 + l4) * 512 + tcol * 8];
        #pragma unroll
        for (int knt = 0; knt < 4; ++knt) {
            half8 kf = *(half8*)&Ku[(h * 4 + l4) * 512 + (knt * 16 + l15) * 8];
            f32x4 z = {0.f, 0.f, 0.f, 0.f};
            s[h][knt] = MFMA_F16(kf, qf, z, 0, 0, 0);
        }
    }
    __syncthreads();   // B3: Q,K dead for ALL waves -> P may overwrite A+B

    // ---- softmax: q uniform per thread; reduce over l4 axis ---------------
    {
        const float scale = 0.17677669529663687f;
        const bool qo = tok_ok;
        const int qcl = qo ? tcol : 48;
        int qi = div7b(qcl), qj = qcl - qi * 7;
        int lqr = labB(wh * WS + qi), lqc = labB(ww * WS + qj);
        bool keep[4][4]; int kcl[4][4];
        #pragma unroll
        for (int knt = 0; knt < 4; ++knt) {
            #pragma unroll
            for (int r = 0; r < 4; ++r) {
                int k = knt * 16 + l4 * 4 + r;
                int kc = k < 49 ? k : 48;
                kcl[knt][r] = kc;
                int ki = div7b(kc), kj = kc - ki * 7;
                keep[knt][r] = qo && (k < 49) &&
                               (lqr == labB(wh * WS + ki)) &&
                               (lqc == labB(ww * WS + kj));
            }
        }
        #pragma unroll
        for (int h = 0; h < 3; ++h) {
            const float* bp = attn_bias + (h * 49 + qcl) * 49;
            float e[4][4], sum = 0.f;
            #pragma unroll
            for (int knt = 0; knt < 4; ++knt)
                #pragma unroll
                for (int r = 0; r < 4; ++r) {
                    float v = fmaf(s[h][knt][r], scale, bp[kcl[knt][r]]);
                    e[knt][r] = keep[knt][r] ? __expf(v) : 0.f;
                    sum += e[knt][r];
                }
            sum += __shfl_xor(sum, 16);
            sum += __shfl_xor(sum, 32);
            float inv = qo ? __builtin_amdgcn_rcpf(sum) : 0.f;
            #pragma unroll
            for (int knt = 0; knt < 4; ++knt) {
                int k0 = knt * 16 + l4 * 4;
                half4 pk;
                #pragma unroll
                for (int r = 0; r < 4; ++r) pk[r] = (_Float16)(e[knt][r] * inv);
                *(half4*)&Pu[(h * 8 + (k0 >> 3)) * 512 + tcol * 8 + (k0 & 7)] = pk;
            }
        }
    }
    // Below: wave-private own-token rows/cols or read-only V; no barriers.

    // ---- PV (transposed: A=V^T, B=P^T): D rows=d, col=q=tcol --------------
    #pragma unroll
    for (int h = 0; h < 3; ++h) {
        half8 pb0 = *(half8*)&Pu[(h * 8 + 0 + l4) * 512 + tcol * 8];
        half8 pb1 = *(half8*)&Pu[(h * 8 + 4 + l4) * 512 + tcol * 8];
        #pragma unroll
        for (int ntd = 0; ntd < 2; ++ntd) {
            f32x4 acc = {0.f, 0.f, 0.f, 0.f};
            half8 va0 = *(half8*)&Vu[(h * 8 + 0 + l4) * 256 + (ntd * 16 + l15) * 8];
            acc = MFMA_F16(va0, pb0, acc, 0, 0, 0);
            half8 va1 = *(half8*)&Vu[(h * 8 + 4 + l4) * 256 + (ntd * 16 + l15) * 8];
            acc = MFMA_F16(va1, pb1, acc, 0, 0, 0);
            int c0 = h * 32 + ntd * 16 + l4 * 4;
            half4 st;
            #pragma unroll
            for (int r = 0; r < 4; ++r) st[r] = (_Float16)acc[r];
            *(half4*)&Ou[(c0 >> 3) * 512 + tcol * 8 + (c0 & 7)] = st;
        }
    }

    // ---- proj (transposed) + residual (float4) -> registers ---------------
    size_t tbase;
    {
        int tt = tcol & 63;
        int i = div7b(tt), j = tt - i * 7;
        int row = wh * WS + i + 3; if (row >= HH) row -= HH;
        int col = ww * WS + j + 3; if (col >= HH) col -= HH;
        tbase = ((size_t)b * HW + row * HH + col) * 96;
    }
    float x2v[6][4];
    {
        half8 ob[3];
        #pragma unroll
        for (int kb = 0; kb < 3; ++kb)
            ob[kb] = *(half8*)&Ou[(kb * 4 + l4) * 512 + tcol * 8];
        #pragma unroll
        for (int nt = 0; nt < 6; ++nt) {
            f32x4 acc = {0.f, 0.f, 0.f, 0.f};
            #pragma unroll
            for (int kb = 0; kb < 3; ++kb) {
                half8 bw = *(const half8*)&projp[((nt * 3 + kb) * 4 + l4) * 128 + l15 * 8];
                acc = MFMA_F16(bw, ob[kb], acc, 0, 0, 0);
            }
            int n0 = nt * 16 + l4 * 4;
            f32x4 pb4 = *(const f32x4*)&proj_b[n0];
            if (tok_ok) {
                f32x4 xr4 = *(const f32x4*)&x[tbase + n0];
                #pragma unroll
                for (int r = 0; r < 4; ++r)
                    x2v[nt][r] = xr4[r] + acc[r] + pb4[r];
            } else {
                #pragma unroll
                for (int r = 0; r < 4; ++r) x2v[nt][r] = 0.f;
            }
        }
    }

    // ---- LN2 in-register: one token/thread; reduce over l4 (2 shuffles) ---
    float mu2, rs2;
    {
        float sum = 0.f, sq = 0.f;
        #pragma unroll
        for (int nt = 0; nt < 6; ++nt)
            #pragma unroll
            for (int r = 0; r < 4; ++r) { float v = x2v[nt][r]; sum += v; sq += v * v; }
        sum += __shfl_xor(sum, 16); sq += __shfl_xor(sq, 16);
        sum += __shfl_xor(sum, 32); sq += __shfl_xor(sq, 32);
        mu2 = sum * (1.0f / 96.0f);
        rs2 = rsqrtf(sq * (1.0f / 96.0f) - mu2 * mu2 + 1e-5f);
    }

    // ---- x^ -> XT tiles (b64, own token rows; over Ou after ob read) ------
    #pragma unroll
    for (int nt = 0; nt < 6; ++nt) {
        int n0 = nt * 16 + l4 * 4;
        half4 st;
        #pragma unroll
        for (int r = 0; r < 4; ++r)
            st[r] = (_Float16)((x2v[nt][r] - mu2) * rs2);
        *(half4*)&XT[(n0 >> 3) * 512 + tcol * 8 + (n0 & 7)] = st;
    }

    // ---- MLP GEMM1 (transposed) + GELU -> YT tiles ------------------------
    {
        half8 xb[3];
        #pragma unroll
        for (int kb = 0; kb < 3; ++kb)
            xb[kb] = *(half8*)&XT[(kb * 4 + l4) * 512 + tcol * 8];
        #pragma unroll
        for (int nt = 0; nt < 6; ++nt) {
            f32x4 acc = {0.f, 0.f, 0.f, 0.f};
            #pragma unroll
            for (int kb = 0; kb < 3; ++kb) {
                half8 bw = *(const half8*)&w1p[((nt * 3 + kb) * 4 + l4) * 128 + l15 * 8];
                acc = MFMA_F16(bw, xb[kb], acc, 0, 0, 0);
            }
            int n0 = nt * 16 + l4 * 4;
            f32x4 b14 = *(const f32x4*)&biasf[288 + n0];
            half4 st;
            #pragma unroll
            for (int r = 0; r < 4; ++r) {
                float v = acc[r] + b14[r];
                // gelu(v) ~= v * sigmoid(v*(1.5957691 + 0.0713548*v^2))
                float v2 = v * v;
                float c2 = fmaf(v2, 0.0713548163f, 1.5957691216f);
                float z  = v * c2;
                float ex = __expf(-z);
                st[r] = (_Float16)(v * __builtin_amdgcn_rcpf(1.0f + ex));
            }
            *(half4*)&YT[(n0 >> 3) * 512 + tcol * 8 + (n0 & 7)] = st;
        }
    }

    // ---- MLP GEMM2 (transposed) + final residual -> out (float4) ----------
    {
        half8 yb[3];
        #pragma unroll
        for (int kb = 0; kb < 3; ++kb)
            yb[kb] = *(half8*)&YT[(kb * 4 + l4) * 512 + tcol * 8];
        #pragma unroll
        for (int nt = 0; nt < 6; ++nt) {
            f32x4 acc = {0.f, 0.f, 0.f, 0.f};
            #pragma unroll
            for (int kb = 0; kb < 3; ++kb) {
                half8 bw = *(const half8*)&w2p[((nt * 3 + kb) * 4 + l4) * 128 + l15 * 8];
                acc = MFMA_F16(bw, yb[kb], acc, 0, 0, 0);
            }
            int n0 = nt * 16 + l4 * 4;
            f32x4 b24 = *(const f32x4*)&mlp_b2[n0];
            if (tok_ok) {
                f32x4 o;
                #pragma unroll
                for (int r = 0; r < 4; ++r)
                    o[r] = x2v[nt][r] + acc[r] + b24[r];
                *(f32x4*)&out[tbase + n0] = o;
            }
        }
    }
}

extern "C" void kernel_launch(void* const* d_in, const int* in_sizes, int n_in,
                              void* d_out, int out_size, void* d_ws, size_t ws_size,
                              hipStream_t stream) {
    (void)in_sizes; (void)n_in; (void)ws_size; (void)out_size;
    const float* x         = (const float*)d_in[0];
    const float* qkv_w     = (const float*)d_in[1];
    const float* qkv_b     = (const float*)d_in[2];
    const float* attn_bias = (const float*)d_in[3];
    const float* proj_w    = (const float*)d_in[4];
    const float* proj_b    = (const float*)d_in[5];
    const float* ln1_g     = (const float*)d_in[6];
    const float* ln1_b     = (const float*)d_in[7];
    const float* ln2_g     = (const float*)d_in[8];
    const float* ln2_b     = (const float*)d_in[9];
    const float* mlp_w1    = (const float*)d_in[10];
    const float* mlp_b1    = (const float*)d_in[11];
    const float* mlp_w2    = (const float*)d_in[12];
    const float* mlp_b2    = (const float*)d_in[13];
    float* out = (float*)d_out;
    _Float16* wpack = (_Float16*)d_ws;
    float* biasf = (float*)((char*)d_ws + BIASF_BYTE);

    pack_wB<<<218, 256, 0, stream>>>(qkv_w, proj_w, mlp_w1, mlp_w2,
                                     ln1_g, ln1_b, ln2_g, ln2_b,
                                     qkv_b, mlp_b1, wpack, biasf);
    attn_kB<<<64 * 64, 256, 0, stream>>>(x, attn_bias, proj_b, mlp_b2,
                                         wpack, biasf, out);
}

// Round 15
// 127.873 us; speedup vs baseline: 1.1098x; 1.0016x over previous
//
#include <hip/hip_runtime.h>
#include <math.h>

typedef _Float16 half8 __attribute__((ext_vector_type(8)));
typedef _Float16 half4 __attribute__((ext_vector_type(4)));
typedef float f32x4 __attribute__((ext_vector_type(4)));

#define MFMA_F16 __builtin_amdgcn_mfma_f32_16x16x32_f16

constexpr int WS = 7, HH = 56, HW = 3136;

// d_ws layout: fp16 tiles then f32 folded biases
constexpr int QKVP_OFF  = 0;       // 27648 fp16
constexpr int PROJP_OFF = 27648;   // 9216
constexpr int W1P_OFF   = 36864;   // 9216
constexpr int W2P_OFF   = 46080;   // 9216 -> 55296 fp16 = 110592 B
constexpr int BIASF_BYTE = 110592; // f32 [288 qkv' | 96 mlp1'] = 1536 B

__device__ __forceinline__ int labC(int v) { return v < 49 ? 0 : (v < 53 ? 1 : 2); }
__device__ __forceinline__ int div7c(int v) { return (v * 9363) >> 16; }  // valid 0..63

// ---------------------------------------------------------------------------
// Weight pre-pack with LN-affine folding (unchanged).
// ---------------------------------------------------------------------------
__global__ __launch_bounds__(256) void pack_wC(
    const float* __restrict__ qkv_w, const float* __restrict__ proj_w,
    const float* __restrict__ w1, const float* __restrict__ w2,
    const float* __restrict__ ln1_g, const float* __restrict__ ln1_b,
    const float* __restrict__ ln2_g, const float* __restrict__ ln2_b,
    const float* __restrict__ qkv_b, const float* __restrict__ mlp_b1,
    _Float16* __restrict__ ws, float* __restrict__ bias_out)
{
    int blk = blockIdx.x;
    if (blk < 216) {
        int i = blk * 256 + threadIdx.x;
        const float* src; int ncol, local; const float* gv = nullptr;
        if (i < 27648)      { src = qkv_w;  ncol = 288; local = i; gv = ln1_g; }
        else if (i < 36864) { src = proj_w; ncol = 96;  local = i - 27648; }
        else if (i < 46080) { src = w1;     ncol = 96;  local = i - 36864; gv = ln2_g; }
        else                { src = w2;     ncol = 96;  local = i - 46080; }
        int j = local & 7, col = (local >> 3) & 15, ksub = (local >> 7) & 3;
        int rest = local >> 9;
        int kb = rest % 3, nt = rest / 3;
        int k = kb * 32 + ksub * 8 + j, n = nt * 16 + col;
        float v = src[k * ncol + n];
        if (gv) v *= gv[k];
        ws[i] = (_Float16)v;
    } else if (blk == 216) {
        int n = threadIdx.x;
        float s = qkv_b[n];
        for (int k = 0; k < 96; ++k) s += ln1_b[k] * qkv_w[k * 288 + n];
        bias_out[n] = s;
    } else {
        int t = threadIdx.x;
        if (t < 32) {
            int n = 256 + t;
            float s = qkv_b[n];
            for (int k = 0; k < 96; ++k) s += ln1_b[k] * qkv_w[k * 288 + n];
            bias_out[n] = s;
        } else if (t < 128) {
            int n = t - 32;
            float s = mlp_b1[n];
            for (int k = 0; k < 96; ++k) s += ln2_b[k] * w1[k * 96 + n];
            bias_out[288 + n] = s;
        }
    }
}

// ---------------------------------------------------------------------------
// Fully fused Swin block, transposed GEMMs (D col = token). TWO barriers:
//   B2 (K/V publish), B3 (Q/K dead -> P overwrite). B1 eliminated: V pad
//   planes (tok 48-63) belong to wave 3's columns only; wave 3 zeroes them
//   before its own V store (in-wave DS order).
// s_setprio(1) wraps the post-B3 MFMA tail (PV..GEMM2) — phase-diverse
// blocks on a CU let the scheduler favor MFMA-issuing waves (T5).
// LDS planes aliased over time (36.9 KB -> 4 blocks/CU):
//   region A [0,12288):      XLN -> Qu -> Pu(lo) -> Ou -> XT
//   region B [12288,24576):  Ku -> Pu(hi) -> YT
//   region V [24576,36864):  Vu
// ---------------------------------------------------------------------------
__global__ __launch_bounds__(256, 4) void attn_kC(
    const float* __restrict__ x,
    const float* __restrict__ attn_bias,
    const float* __restrict__ proj_b,
    const float* __restrict__ mlp_b2,
    const _Float16* __restrict__ wpack,
    const float* __restrict__ biasf,
    float* __restrict__ out)
{
    __shared__ __align__(16) char smem[36864];

    _Float16*  XLN = (_Float16*)smem;
    _Float16*  Qu  = (_Float16*)smem;
    _Float16*  Ku  = (_Float16*)(smem + 12288);
    _Float16*  Vu  = (_Float16*)(smem + 24576);
    _Float16*  Pu  = (_Float16*)smem;            // 24 planes spanning A+B
    _Float16*  Ou  = (_Float16*)smem;            // planes 0..11
    _Float16*  XT  = (_Float16*)smem;
    _Float16*  YT  = (_Float16*)(smem + 12288);

    const _Float16* qkvp  = wpack + QKVP_OFF;
    const _Float16* projp = wpack + PROJP_OFF;
    const _Float16* w1p   = wpack + W1P_OFF;
    const _Float16* w2p   = wpack + W2P_OFF;

    const int blk = blockIdx.x;
    const int b   = blk >> 6;
    const int w   = blk & 63;
    const int wh  = w >> 3, ww = w & 7;
    const int tid = threadIdx.x;
    const int wv  = tid >> 6, lane = tid & 63;
    const int l15 = lane & 15, l4 = lane >> 4;

    const int  tcol   = wv * 16 + l15;     // this thread's token (D column)
    const bool tok_ok = tcol < 49;

    // ---- wave 3 zeroes V pad planes (tok 48-55 grp6, 56-63 grp7) ----------
    // Pad columns are wave 3's own (tcol>=48 <=> wv==3); tok48's real data is
    // stored later BY WAVE 3 (in-wave order). No barrier needed.
    if (wv == 3) {
        uint4* v4 = (uint4*)Vu;
        #pragma unroll
        for (int h = 0; h < 3; ++h)
            v4[(h * 8 + 6) * 32 + lane] = make_uint4(0, 0, 0, 0); // 2 planes/h
    }

    // ---- gather window (rolled) into registers: 4 threads/token ----------
    const int t_own = tid >> 2, part = tid & 3;
    const bool active = (tid < 196);
    float4 xq[6];
    float m = 0.f, rinv = 0.f;
    if (active) {
        int i = div7c(t_own), j = t_own - i * 7;
        int row = wh * WS + i + 3; if (row >= HH) row -= HH;
        int col = ww * WS + j + 3; if (col >= HH) col -= HH;
        const float* xp = &x[(((size_t)b * HW + row * HH + col) * 96) + part * 24];
        #pragma unroll
        for (int q = 0; q < 6; ++q) xq[q] = *(const float4*)&xp[q * 4];
        float sum = 0.f, sq = 0.f;
        #pragma unroll
        for (int q = 0; q < 6; ++q) {
            sum += xq[q].x + xq[q].y + xq[q].z + xq[q].w;
            sq  += xq[q].x * xq[q].x + xq[q].y * xq[q].y
                 + xq[q].z * xq[q].z + xq[q].w * xq[q].w;
        }
        sum += __shfl_xor(sum, 1); sq += __shfl_xor(sq, 1);
        sum += __shfl_xor(sum, 2); sq += __shfl_xor(sq, 2);
        m = sum * (1.0f / 96.0f);
        rinv = rsqrtf(sq * (1.0f / 96.0f) - m * m + 1e-5f);
    }

    // ---- normalize (affine folded) -> XLN tiles (own-wave rows) -----------
    if (active) {
        #pragma unroll
        for (int cc = 0; cc < 3; ++cc) {
            half8 pk;
            #pragma unroll
            for (int j = 0; j < 8; ++j) {
                float v; int qi = cc * 2 + (j >> 2);
                if ((j & 3) == 0) v = xq[qi].x;
                else if ((j & 3) == 1) v = xq[qi].y;
                else if ((j & 3) == 2) v = xq[qi].z;
                else v = xq[qi].w;
                pk[j] = (_Float16)((v - m) * rinv);
            }
            *(half8*)&XLN[(part * 3 + cc) * 512 + t_own * 8] = pk;
        }
    }
    // NO barrier: B-frag cols below are own-wave tokens.

    // ---- QKV GEMM (transposed: A=W^T, B=XLN; D rows=channels, col=token) --
    {
        half8 bx[3];
        #pragma unroll
        for (int kb = 0; kb < 3; ++kb)
            bx[kb] = *(half8*)&XLN[(kb * 4 + l4) * 512 + tcol * 8];

        // Q: nt 0..5 -> b64 stores (pad-token cols garbage, masked later)
        #pragma unroll
        for (int nt = 0; nt < 6; ++nt) {
            f32x4 acc = {0.f, 0.f, 0.f, 0.f};
            #pragma unroll
            for (int kb = 0; kb < 3; ++kb) {
                half8 bw = *(const half8*)&qkvp[((nt * 3 + kb) * 4 + l4) * 128 + l15 * 8];
                acc = MFMA_F16(bw, bx[kb], acc, 0, 0, 0);
            }
            int n0 = nt * 16 + l4 * 4;
            f32x4 b4 = *(const f32x4*)&biasf[n0];
            int h = n0 >> 5, d0 = n0 & 31;
            half4 st;
            #pragma unroll
            for (int r = 0; r < 4; ++r) st[r] = (_Float16)(acc[r] + b4[r]);
            *(half4*)&Qu[(h * 4 + (d0 >> 3)) * 512 + tcol * 8 + (d0 & 7)] = st;
        }
        // K: nt 6..11
        #pragma unroll
        for (int nt = 6; nt < 12; ++nt) {
            f32x4 acc = {0.f, 0.f, 0.f, 0.f};
            #pragma unroll
            for (int kb = 0; kb < 3; ++kb) {
                half8 bw = *(const half8*)&qkvp[((nt * 3 + kb) * 4 + l4) * 128 + l15 * 8];
                acc = MFMA_F16(bw, bx[kb], acc, 0, 0, 0);
            }
            int n0 = nt * 16 + l4 * 4;
            f32x4 b4 = *(const f32x4*)&biasf[n0];
            int n2 = n0 - 96, h = n2 >> 5, d0 = n2 & 31;
            half4 st;
            #pragma unroll
            for (int r = 0; r < 4; ++r) st[r] = (_Float16)(acc[r] + b4[r]);
            *(half4*)&Ku[(h * 4 + (d0 >> 3)) * 512 + tcol * 8 + (d0 & 7)] = st;
        }
        // V: nt 12..17 (uniform per-thread guard; pad cols stay zero)
        #pragma unroll
        for (int nt = 12; nt < 18; ++nt) {
            f32x4 acc = {0.f, 0.f, 0.f, 0.f};
            #pragma unroll
            for (int kb = 0; kb < 3; ++kb) {
                half8 bw = *(const half8*)&qkvp[((nt * 3 + kb) * 4 + l4) * 128 + l15 * 8];
                acc = MFMA_F16(bw, bx[kb], acc, 0, 0, 0);
            }
            int n0 = nt * 16 + l4 * 4;
            f32x4 b4 = *(const f32x4*)&biasf[n0];
            int n2 = n0 - 192, h = n2 >> 5, d0 = n2 & 31;
            if (tok_ok) {
                int vb = (h * 8 + (tcol >> 3)) * 256 + d0 * 8 + (tcol & 7);
                #pragma unroll
                for (int r = 0; r < 4; ++r)
                    Vu[vb + r * 8] = (_Float16)(acc[r] + b4[r]);
            }
        }
    }
    __syncthreads();   // B2: K/V published for cross-wave reads

    // ---- scores (transposed: A=K, B=Q): D rows=k, col=q=tcol --------------
    f32x4 s[3][4];
    #pragma unroll
    for (int h = 0; h < 3; ++h) {
        half8 qf = *(half8*)&Qu[(h * 4 + l4) * 512 + tcol * 8];
        #pragma unroll
        for (int knt = 0; knt < 4; ++knt) {
            half8 kf = *(half8*)&Ku[(h * 4 + l4) * 512 + (knt * 16 + l15) * 8];
            f32x4 z = {0.f, 0.f, 0.f, 0.f};
            s[h][knt] = MFMA_F16(kf, qf, z, 0, 0, 0);
        }
    }
    __syncthreads();   // B3: Q,K dead for ALL waves -> P may overwrite A+B

    // ---- softmax: q uniform per thread; reduce over l4 axis ---------------
    {
        const float scale = 0.17677669529663687f;
        const bool qo = tok_ok;
        const int qcl = qo ? tcol : 48;
        int qi = div7c(qcl), qj = qcl - qi * 7;
        int lqr = labC(wh * WS + qi), lqc = labC(ww * WS + qj);
        bool keep[4][4]; int kcl[4][4];
        #pragma unroll
        for (int knt = 0; knt < 4; ++knt) {
            #pragma unroll
            for (int r = 0; r < 4; ++r) {
                int k = knt * 16 + l4 * 4 + r;
                int kc = k < 49 ? k : 48;
                kcl[knt][r] = kc;
                int ki = div7c(kc), kj = kc - ki * 7;
                keep[knt][r] = qo && (k < 49) &&
                               (lqr == labC(wh * WS + ki)) &&
                               (lqc == labC(ww * WS + kj));
            }
        }
        #pragma unroll
        for (int h = 0; h < 3; ++h) {
            const float* bp = attn_bias + (h * 49 + qcl) * 49;
            float e[4][4], sum = 0.f;
            #pragma unroll
            for (int knt = 0; knt < 4; ++knt)
                #pragma unroll
                for (int r = 0; r < 4; ++r) {
                    float v = fmaf(s[h][knt][r], scale, bp[kcl[knt][r]]);
                    e[knt][r] = keep[knt][r] ? __expf(v) : 0.f;
                    sum += e[knt][r];
                }
            sum += __shfl_xor(sum, 16);
            sum += __shfl_xor(sum, 32);
            float inv = qo ? __builtin_amdgcn_rcpf(sum) : 0.f;
            #pragma unroll
            for (int knt = 0; knt < 4; ++knt) {
                int k0 = knt * 16 + l4 * 4;
                half4 pk;
                #pragma unroll
                for (int r = 0; r < 4; ++r) pk[r] = (_Float16)(e[knt][r] * inv);
                *(half4*)&Pu[(h * 8 + (k0 >> 3)) * 512 + tcol * 8 + (k0 & 7)] = pk;
            }
        }
    }
    // Below: wave-private own-token rows/cols or read-only V; no barriers.
    __builtin_amdgcn_s_setprio(1);   // MFMA-dense tail: favor these waves

    // ---- PV (transposed: A=V^T, B=P^T): D rows=d, col=q=tcol --------------
    #pragma unroll
    for (int h = 0; h < 3; ++h) {
        half8 pb0 = *(half8*)&Pu[(h * 8 + 0 + l4) * 512 + tcol * 8];
        half8 pb1 = *(half8*)&Pu[(h * 8 + 4 + l4) * 512 + tcol * 8];
        #pragma unroll
        for (int ntd = 0; ntd < 2; ++ntd) {
            f32x4 acc = {0.f, 0.f, 0.f, 0.f};
            half8 va0 = *(half8*)&Vu[(h * 8 + 0 + l4) * 256 + (ntd * 16 + l15) * 8];
            acc = MFMA_F16(va0, pb0, acc, 0, 0, 0);
            half8 va1 = *(half8*)&Vu[(h * 8 + 4 + l4) * 256 + (ntd * 16 + l15) * 8];
            acc = MFMA_F16(va1, pb1, acc, 0, 0, 0);
            int c0 = h * 32 + ntd * 16 + l4 * 4;
            half4 st;
            #pragma unroll
            for (int r = 0; r < 4; ++r) st[r] = (_Float16)acc[r];
            *(half4*)&Ou[(c0 >> 3) * 512 + tcol * 8 + (c0 & 7)] = st;
        }
    }

    // ---- proj (transposed) + residual (float4) -> registers ---------------
    size_t tbase;
    {
        int tt = tcol & 63;
        int i = div7c(tt), j = tt - i * 7;
        int row = wh * WS + i + 3; if (row >= HH) row -= HH;
        int col = ww * WS + j + 3; if (col >= HH) col -= HH;
        tbase = ((size_t)b * HW + row * HH + col) * 96;
    }
    float x2v[6][4];
    {
        half8 ob[3];
        #pragma unroll
        for (int kb = 0; kb < 3; ++kb)
            ob[kb] = *(half8*)&Ou[(kb * 4 + l4) * 512 + tcol * 8];
        #pragma unroll
        for (int nt = 0; nt < 6; ++nt) {
            f32x4 acc = {0.f, 0.f, 0.f, 0.f};
            #pragma unroll
            for (int kb = 0; kb < 3; ++kb) {
                half8 bw = *(const half8*)&projp[((nt * 3 + kb) * 4 + l4) * 128 + l15 * 8];
                acc = MFMA_F16(bw, ob[kb], acc, 0, 0, 0);
            }
            int n0 = nt * 16 + l4 * 4;
            f32x4 pb4 = *(const f32x4*)&proj_b[n0];
            if (tok_ok) {
                f32x4 xr4 = *(const f32x4*)&x[tbase + n0];
                #pragma unroll
                for (int r = 0; r < 4; ++r)
                    x2v[nt][r] = xr4[r] + acc[r] + pb4[r];
            } else {
                #pragma unroll
                for (int r = 0; r < 4; ++r) x2v[nt][r] = 0.f;
            }
        }
    }

    // ---- LN2 in-register: one token/thread; reduce over l4 (2 shuffles) ---
    float mu2, rs2;
    {
        float sum = 0.f, sq = 0.f;
        #pragma unroll
        for (int nt = 0; nt < 6; ++nt)
            #pragma unroll
            for (int r = 0; r < 4; ++r) { float v = x2v[nt][r]; sum += v; sq += v * v; }
        sum += __shfl_xor(sum, 16); sq += __shfl_xor(sq, 16);
        sum += __shfl_xor(sum, 32); sq += __shfl_xor(sq, 32);
        mu2 = sum * (1.0f / 96.0f);
        rs2 = rsqrtf(sq * (1.0f / 96.0f) - mu2 * mu2 + 1e-5f);
    }

    // ---- x^ -> XT tiles (b64, own token rows; over Ou after ob read) ------
    #pragma unroll
    for (int nt = 0; nt < 6; ++nt) {
        int n0 = nt * 16 + l4 * 4;
        half4 st;
        #pragma unroll
        for (int r = 0; r < 4; ++r)
            st[r] = (_Float16)((x2v[nt][r] - mu2) * rs2);
        *(half4*)&XT[(n0 >> 3) * 512 + tcol * 8 + (n0 & 7)] = st;
    }

    // ---- MLP GEMM1 (transposed) + GELU -> YT tiles ------------------------
    {
        half8 xb[3];
        #pragma unroll
        for (int kb = 0; kb < 3; ++kb)
            xb[kb] = *(half8*)&XT[(kb * 4 + l4) * 512 + tcol * 8];
        #pragma unroll
        for (int nt = 0; nt < 6; ++nt) {
            f32x4 acc = {0.f, 0.f, 0.f, 0.f};
            #pragma unroll
            for (int kb = 0; kb < 3; ++kb) {
                half8 bw = *(const half8*)&w1p[((nt * 3 + kb) * 4 + l4) * 128 + l15 * 8];
                acc = MFMA_F16(bw, xb[kb], acc, 0, 0, 0);
            }
            int n0 = nt * 16 + l4 * 4;
            f32x4 b14 = *(const f32x4*)&biasf[288 + n0];
            half4 st;
            #pragma unroll
            for (int r = 0; r < 4; ++r) {
                float v = acc[r] + b14[r];
                // gelu(v) ~= v * sigmoid(v*(1.5957691 + 0.0713548*v^2))
                float v2 = v * v;
                float c2 = fmaf(v2, 0.0713548163f, 1.5957691216f);
                float z  = v * c2;
                float ex = __expf(-z);
                st[r] = (_Float16)(v * __builtin_amdgcn_rcpf(1.0f + ex));
            }
            *(half4*)&YT[(n0 >> 3) * 512 + tcol * 8 + (n0 & 7)] = st;
        }
    }

    // ---- MLP GEMM2 (transposed) + final residual -> out (float4) ----------
    {
        half8 yb[3];
        #pragma unroll
        for (int kb = 0; kb < 3; ++kb)
            yb[kb] = *(half8*)&YT[(kb * 4 + l4) * 512 + tcol * 8];
        #pragma unroll
        for (int nt = 0; nt < 6; ++nt) {
            f32x4 acc = {0.f, 0.f, 0.f, 0.f};
            #pragma unroll
            for (int kb = 0; kb < 3; ++kb) {
                half8 bw = *(const half8*)&w2p[((nt * 3 + kb) * 4 + l4) * 128 + l15 * 8];
                acc = MFMA_F16(bw, yb[kb], acc, 0, 0, 0);
            }
            int n0 = nt * 16 + l4 * 4;
            f32x4 b24 = *(const f32x4*)&mlp_b2[n0];
            if (tok_ok) {
                f32x4 o;
                #pragma unroll
                for (int r = 0; r < 4; ++r)
                    o[r] = x2v[nt][r] + acc[r] + b24[r];
                *(f32x4*)&out[tbase + n0] = o;
            }
        }
    }
    __builtin_amdgcn_s_setprio(0);
}

extern "C" void kernel_launch(void* const* d_in, const int* in_sizes, int n_in,
                              void* d_out, int out_size, void* d_ws, size_t ws_size,
                              hipStream_t stream) {
    (void)in_sizes; (void)n_in; (void)ws_size; (void)out_size;
    const float* x         = (const float*)d_in[0];
    const float* qkv_w     = (const float*)d_in[1];
    const float* qkv_b     = (const float*)d_in[2];
    const float* attn_bias = (const float*)d_in[3];
    const float* proj_w    = (const float*)d_in[4];
    const float* proj_b    = (const float*)d_in[5];
    const float* ln1_g     = (const float*)d_in[6];
    const float* ln1_b     = (const float*)d_in[7];
    const float* ln2_g     = (const float*)d_in[8];
    const float* ln2_b     = (const float*)d_in[9];
    const float* mlp_w1    = (const float*)d_in[10];
    const float* mlp_b1    = (const float*)d_in[11];
    const float* mlp_w2    = (const float*)d_in[12];
    const float* mlp_b2    = (const float*)d_in[13];
    float* out = (float*)d_out;
    _Float16* wpack = (_Float16*)d_ws;
    float* biasf = (float*)((char*)d_ws + BIASF_BYTE);

    pack_wC<<<218, 256, 0, stream>>>(qkv_w, proj_w, mlp_w1, mlp_w2,
                                     ln1_g, ln1_b, ln2_g, ln2_b,
                                     qkv_b, mlp_b1, wpack, biasf);
    attn_kC<<<64 * 64, 256, 0, stream>>>(x, attn_bias, proj_b, mlp_b2,
                                         wpack, biasf, out);
}